// Round 10
// baseline (1247.760 us; speedup 1.0000x reference)
//
#include <hip/hip_runtime.h>

#define DIMS 3
#define NB 256
#define NN 256
#define KK 16
#define HID 64
#define EPG 8192
#define NTOT (NB*NN)
#define NE (NB*EPG)

// d_out layout (flat concat of reference outputs, all as float)
#define PX_OFF   0          // (B*K, F, DIMS)           = 786432
#define PEI_OFF  786432     // (2, B*K*K)               = 131072
#define PEA_OFF  917504     // (B*K*K, DIMS)            = 196608
#define PB_OFF   1114112    // (B*K,)                   = 4096
#define LOSS_OFF 1118208    // scalar
#define S_OFF    1118209    // (DIMS, B, N, K)          = 3145728

// d_ws layout (bytes) — total ~27.5 MB
#define WREC_WS  0                 // float[3][NB*EPG] per-d edge weight (CSR order) = 24 MB
#define CLREC_WS 25165824          // uchar[NB*EPG] col-local index
#define IPTR_WS  27262976          // int[NB*257]
#define ENT_WS   27526144          // float[768]
#define MOD_WS   27529216          // float[768]
#define WC_WS    27532288          // float[144*16]  (fcW1 @ fcW2)
#define BC_WS    27541504          // float[16]      (fcb1 @ fcW2 + fcb2)

// ---------------- combined FC weights: Wc = fcW1@fcW2, bc = fcb1@fcW2+fcb2 ----------------
__global__ void fc_combine(const float* __restrict__ fcW1, const float* __restrict__ fcb1,
                           const float* __restrict__ fcW2, const float* __restrict__ fcb2,
                           float* __restrict__ wc, float* __restrict__ bc)
{
    const int t = threadIdx.x;
    for (int idx = t; idx < 144 * 16; idx += 256) {
        const int i = idx >> 4, k = idx & 15;
        float s = 0.f;
        for (int q = 0; q < 50; ++q) s += fcW1[i * 50 + q] * fcW2[q * 16 + k];
        wc[idx] = s;
    }
    if (t < 16) {
        float s = fcb2[t];
        for (int q = 0; q < 50; ++q) s += fcb1[q] * fcW2[q * 16 + t];
        bc[t] = s;
    }
}

// ------- CSR build: parallel deterministic counting sort (strided chunks) -------
#define HSTR 132
#define PSTR 129
__launch_bounds__(256)
__global__ void csr_build(const int* __restrict__ edge_index,
                          const float* __restrict__ edge_attr,
                          float* __restrict__ wrec, unsigned char* __restrict__ clrec,
                          int* __restrict__ indptr)
{
    __shared__ unsigned char  h[256 * HSTR];    // 33.8 KB
    __shared__ unsigned short po[256 * PSTR];   // 66.0 KB
    __shared__ int sc[256];
    const int b = blockIdx.x;
    const int t = threadIdx.x;
    const int* rowp = edge_index + (size_t)b * EPG;
    const int* colp = edge_index + (size_t)NB * EPG + (size_t)b * EPG;

    for (int i = t; i < 256 * HSTR / 4; i += 256) ((unsigned int*)h)[i] = 0u;
    __syncthreads();

    if (t < 128) {
        #pragma unroll 4
        for (int j = 0; j < 64; ++j) {
            const int r = rowp[t + 128 * j] & (NN - 1);
            h[r * HSTR + t]++;
        }
    }
    __syncthreads();

    int tot;
    {
        int s = 0;
        const unsigned int* hr = (const unsigned int*)(h + t * HSTR);
        #pragma unroll
        for (int c4 = 0; c4 < HSTR / 4; ++c4) {
            const unsigned int v = hr[c4];
            s += (v & 255) + ((v >> 8) & 255) + ((v >> 16) & 255) + (v >> 24);
        }
        tot = s;
        sc[t] = s;
    }
    __syncthreads();
    for (int ofs = 1; ofs < 256; ofs <<= 1) {
        int v = (t >= ofs) ? sc[t - ofs] : 0;
        __syncthreads();
        sc[t] += v;
        __syncthreads();
    }
    const int start = sc[t] - tot;
    indptr[b * 257 + t] = start;
    if (t == 255) indptr[b * 257 + 256] = EPG;

    {
        int run = start;
        #pragma unroll 4
        for (int c = 0; c < 128; ++c) {
            po[t * PSTR + c] = (unsigned short)run;
            run += h[t * HSTR + c];
        }
    }
    __syncthreads();

    if (t < 128) {
        const float* eap = edge_attr + (size_t)b * EPG * 3;
        float* w0 = wrec + (size_t)b * EPG;
        float* w1 = wrec + (size_t)NB * EPG + (size_t)b * EPG;
        float* w2 = wrec + 2 * (size_t)NB * EPG + (size_t)b * EPG;
        unsigned char* cdst = clrec + (size_t)b * EPG;
        #pragma unroll 2
        for (int j = 0; j < 64; ++j) {
            const int e = t + 128 * j;
            const int r = rowp[e] & (NN - 1);
            const int cl = colp[e] & (NN - 1);
            const int dest = po[r * PSTR + t]++;
            w0[dest] = eap[e * 3 + 0];
            w1[dest] = eap[e * 3 + 1];
            w2[dest] = eap[e * 3 + 2];
            cdst[dest] = (unsigned char)cl;
        }
    }
}

// -------- gconv: 1024 thr, thread = (r, q) = (t>>2, t&3). Merged dense pass (weights
// from GLOBAL/L1); FC accumulation is a separate post-barrier phase that re-reads h_next
// from LDS (peak live ~56 regs in dense, ~24 in FC -> no spill at the 64-VGPR budget).
// L2's h (not stored to hb) is parked in the dead agg buffer for its FC phase. --------
template<int OUTW, bool WRITE_H>
__device__ __forceinline__ void layer_step(
    int r, int q, int js, int je,
    const float* __restrict__ wp, const unsigned char* __restrict__ clp,
    const float* __restrict__ Wm, const float* __restrict__ Ws,
    const float* __restrict__ bias, const float* __restrict__ wc, // wc + layer_row_off*16
    float4* hb4, float4* ab4, float* lgl)
{
    constexpr int NCOL = OUTW / 4;
    const int rbase = r * 16, rsw = r & 15;
    const int cb = q * 4;

    // P1: gather agg (input channels q*16..+16) over row r's CSR edges
    float ga[16];
    #pragma unroll
    for (int u = 0; u < 16; ++u) ga[u] = 0.f;
    for (int j = js; j < je; ++j) {
        const int cl = clp[j];
        const float w = wp[j];
        const int base = cl * 16, sw = cl & 15;
        #pragma unroll
        for (int u = 0; u < 4; ++u) {
            const float4 h4 = hb4[base + ((cb + u) ^ sw)];
            ga[u*4+0] += w * h4.x; ga[u*4+1] += w * h4.y;
            ga[u*4+2] += w * h4.z; ga[u*4+3] += w * h4.w;
        }
    }
    #pragma unroll
    for (int u = 0; u < 4; ++u) {
        float4 v; v.x = ga[u*4+0]; v.y = ga[u*4+1]; v.z = ga[u*4+2]; v.w = ga[u*4+3];
        ab4[rbase + ((cb + u) ^ rsw)] = v;
    }
    __syncthreads();                          // [B1] agg visible

    // P2: merged dense: acc = bias + h@Ws + agg@Wm ; weights streamed from global (L1)
    const int j0 = q * NCOL;
    float acc[NCOL];
    {
        const float4* bv = (const float4*)(bias + j0);
        #pragma unroll
        for (int q4 = 0; q4 < NCOL / 4; ++q4) {
            const float4 b4 = bv[q4];
            acc[q4*4+0] = b4.x; acc[q4*4+1] = b4.y; acc[q4*4+2] = b4.z; acc[q4*4+3] = b4.w;
        }
    }
    for (int ic = 0; ic < 16; ++ic) {
        const float4 h4 = hb4[rbase + (ic ^ rsw)];
        const float4 a4 = ab4[rbase + (ic ^ rsw)];
        const float hv[4] = {h4.x, h4.y, h4.z, h4.w};
        const float av[4] = {a4.x, a4.y, a4.z, a4.w};
        #pragma unroll
        for (int u = 0; u < 4; ++u) {
            const int i = ic * 4 + u;
            const float* wmr = Wm + i * OUTW + j0;
            const float* wsr = Ws + i * OUTW + j0;
            const float hh = hv[u], aa = av[u];
            #pragma unroll
            for (int q4 = 0; q4 < NCOL / 4; ++q4) {
                const float4 wm4 = *(const float4*)(wmr + q4 * 4);
                const float4 ws4 = *(const float4*)(wsr + q4 * 4);
                acc[q4*4+0] += aa * wm4.x + hh * ws4.x;
                acc[q4*4+1] += aa * wm4.y + hh * ws4.y;
                acc[q4*4+2] += aa * wm4.z + hh * ws4.z;
                acc[q4*4+3] += aa * wm4.w + hh * ws4.w;
            }
        }
    }
    #pragma unroll
    for (int jj = 0; jj < NCOL; ++jj) acc[jj] = fmaxf(acc[jj], 0.f);
    __syncthreads();                          // [B2] all hb/ab reads done

    // P3: write h_next (L0/L1 -> hb4; L2 -> dead agg buffer)
    if (WRITE_H) {
        #pragma unroll
        for (int u = 0; u < NCOL / 4; ++u) {
            float4 v; v.x = acc[u*4+0]; v.y = acc[u*4+1]; v.z = acc[u*4+2]; v.w = acc[u*4+3];
            hb4[rbase + ((cb + u) ^ rsw)] = v;
        }
    } else {
        float4 v; v.x = acc[0]; v.y = acc[1]; v.z = acc[2]; v.w = acc[3];
        ab4[rbase + (q ^ rsw)] = v;
    }
    __syncthreads();                          // [B3] h_next visible

    // P4: FC phase — re-read h_next from LDS, accumulate p[16], quad-reduce, q0 RMWs lgl
    {
        float p[16];
        #pragma unroll
        for (int k = 0; k < 16; ++k) p[k] = 0.f;
        if (WRITE_H) {
            #pragma unroll
            for (int u = 0; u < 4; ++u) {
                const float4 v4 = hb4[rbase + ((cb + u) ^ rsw)];
                const float vv[4] = {v4.x, v4.y, v4.z, v4.w};
                #pragma unroll
                for (int e = 0; e < 4; ++e) {
                    const float a = vv[e];
                    const float* wr = wc + (j0 + u * 4 + e) * 16;
                    #pragma unroll
                    for (int q4 = 0; q4 < 4; ++q4) {
                        const float4 w4 = *(const float4*)(wr + q4 * 4);
                        p[q4*4+0] += a * w4.x; p[q4*4+1] += a * w4.y;
                        p[q4*4+2] += a * w4.z; p[q4*4+3] += a * w4.w;
                    }
                }
            }
        } else {
            const float4 v4 = ab4[rbase + (q ^ rsw)];
            const float vv[4] = {v4.x, v4.y, v4.z, v4.w};
            #pragma unroll
            for (int e = 0; e < 4; ++e) {
                const float a = vv[e];
                const float* wr = wc + (j0 + e) * 16;
                #pragma unroll
                for (int q4 = 0; q4 < 4; ++q4) {
                    const float4 w4 = *(const float4*)(wr + q4 * 4);
                    p[q4*4+0] += a * w4.x; p[q4*4+1] += a * w4.y;
                    p[q4*4+2] += a * w4.z; p[q4*4+3] += a * w4.w;
                }
            }
        }
        #pragma unroll
        for (int k = 0; k < 16; ++k) p[k] += __shfl_xor(p[k], 1);
        #pragma unroll
        for (int k = 0; k < 16; ++k) p[k] += __shfl_xor(p[k], 2);
        if (q == 0) {
            float* Lr = lgl + r * 17;
            #pragma unroll
            for (int k = 0; k < 16; ++k) Lr[k] += p[k];
        }
    }
    // no barrier needed: next phase's first reads (hb4) are fenced by [B3]; lgl is single-owner
}

__launch_bounds__(1024)
__global__ void gconv_kernel(
    const float* __restrict__ x,
    const float* __restrict__ Wm0, const float* __restrict__ Ws0, const float* __restrict__ b0,
    const float* __restrict__ Wm1, const float* __restrict__ Ws1, const float* __restrict__ b1,
    const float* __restrict__ Wm2, const float* __restrict__ Ws2, const float* __restrict__ b2,
    const float* __restrict__ wcomb, const float* __restrict__ bcomb,
    const float* __restrict__ wrec, const unsigned char* __restrict__ clrec,
    const int* __restrict__ indptr,
    float* __restrict__ out, float* __restrict__ entpart)
{
    __shared__ float4 hb4[4096];       // h tile, XOR-chunk-swizzled (64 KB)
    __shared__ float4 ab4[4096];       // agg tile / L2-h parking (64 KB)
    __shared__ float  lgl[NN * 17];    // logits accumulator (17 KB)
    __shared__ float  red[16];
    const int t = threadIdx.x;
    const int bid = blockIdx.x;
    const int d = bid >> 8;
    const int b = bid & (NB - 1);
    const int r = t >> 2;          // row
    const int q = t & 3;           // channel quarter
    const int lane = t & 63;
    const int wave = t >> 6;

    // stage x -> hb (swizzled) ; zero logits
    {
        const float4* xv = (const float4*)(x + (size_t)b * NN * HID);
        #pragma unroll
        for (int it = 0; it < 4; ++it) {
            const int idx = t + it * 1024;
            const int nrow = idx >> 4, c = idx & 15;
            hb4[nrow * 16 + (c ^ (nrow & 15))] = xv[idx];
        }
        for (int i = t; i < NN * 17; i += 1024) lgl[i] = 0.f;
    }
    __syncthreads();   // [B0]

    const float* wp = wrec + (size_t)d * NB * EPG + (size_t)b * EPG;
    const unsigned char* clp = clrec + (size_t)b * EPG;
    const int js = indptr[b * 257 + r];
    const int je = indptr[b * 257 + r + 1];

    layer_step<64, true >(r, q, js, je, wp, clp, Wm0 + d*HID*HID, Ws0 + d*HID*HID,
                          b0 + d*HID, wcomb,            hb4, ab4, lgl);
    layer_step<64, true >(r, q, js, je, wp, clp, Wm1 + d*HID*HID, Ws1 + d*HID*HID,
                          b1 + d*HID, wcomb + 64*16,    hb4, ab4, lgl);
    layer_step<16, false>(r, q, js, je, wp, clp, Wm2 + d*HID*KK,  Ws2 + d*HID*KK,
                          b2 + d*KK,  wcomb + 128*16,   hb4, ab4, lgl);
    __syncthreads();   // lgl complete

    // softmax + entropy: threads t<256, row = t
    float ent_local = 0.f;
    if (t < 256) {
        const int rr = t;
        float logits[KK];
        const float* Lr = lgl + rr * 17;
        #pragma unroll
        for (int k = 0; k < KK; ++k) logits[k] = Lr[k] + bcomb[k];
        float m = logits[0];
        #pragma unroll
        for (int k = 1; k < KK; ++k) m = fmaxf(m, logits[k]);
        float sum = 0.f, sv[KK];
        #pragma unroll
        for (int k = 0; k < KK; ++k) { sv[k] = expf(logits[k] - m); sum += sv[k]; }
        const float inv = 1.f / sum;
        float4* sp4 = (float4*)(out + S_OFF + ((size_t)(d * NB + b) * NN + rr) * KK);
        #pragma unroll
        for (int q4 = 0; q4 < 4; ++q4) {
            float4 v;
            const float s0 = sv[q4*4+0] * inv, s1 = sv[q4*4+1] * inv;
            const float s2 = sv[q4*4+2] * inv, s3 = sv[q4*4+3] * inv;
            v.x = s0; v.y = s1; v.z = s2; v.w = s3;
            sp4[q4] = v;
            ent_local -= s0 * logf(s0 + 1e-15f) + s1 * logf(s1 + 1e-15f)
                       + s2 * logf(s2 + 1e-15f) + s3 * logf(s3 + 1e-15f);
        }
    }
    #pragma unroll
    for (int off = 32; off; off >>= 1) ent_local += __shfl_down(ent_local, off);
    if (lane == 0) red[wave] = ent_local;
    __syncthreads();
    if (t == 0) {
        float s = 0.f;
        #pragma unroll
        for (int w = 0; w < 16; ++w) s += red[w];
        entpart[bid] = s;
    }
}

// ---------------- pool: padj = sum_r s[r] (x) G[r], G = A s ; + mod + px ----------------
#define SSTR 20
__launch_bounds__(256)
__global__ void pool_kernel(
    const float* __restrict__ x_to_pool,
    const float* __restrict__ wrec, const unsigned char* __restrict__ clrec,
    const int* __restrict__ indptr,
    const float* __restrict__ out_s, float* __restrict__ out, float* __restrict__ modpart)
{
    __shared__ float sl[NN * SSTR];       // 20 KB
    __shared__ float gl[NN * SSTR];       // 20 KB
    __shared__ float padjw[4 * 256];      // per-wave partials (deterministic merge)
    __shared__ float red[4];
    const int t = threadIdx.x;
    const int bid = blockIdx.x;
    const int d = bid >> 8;
    const int b = bid & (NB - 1);
    const int lane = t & 63;
    const int wave = t >> 6;

    {
        const float4* sp4 = (const float4*)(out_s + S_OFF + (size_t)(d * NB + b) * NN * KK);
        #pragma unroll
        for (int it = 0; it < 4; ++it) {
            const int idx = t + it * 256;
            const int nrow = idx >> 2, c = idx & 3;
            *(float4*)(sl + nrow * SSTR + c * 4) = sp4[idx];
        }
    }
    __syncthreads();

    const float* wp = wrec + (size_t)d * NB * EPG + (size_t)b * EPG;
    const unsigned char* clp = clrec + (size_t)b * EPG;
    const int js = indptr[b * 257 + t];
    const int je = indptr[b * 257 + t + 1];
    float sr[16];
    {
        #pragma unroll
        for (int c = 0; c < 4; ++c) {
            const float4 v = *(const float4*)(sl + t * SSTR + c * 4);
            sr[c*4+0] = v.x; sr[c*4+1] = v.y; sr[c*4+2] = v.z; sr[c*4+3] = v.w;
        }
    }
    float g[16];
    #pragma unroll
    for (int k = 0; k < 16; ++k) g[k] = 0.f;
    float modacc = 0.f;
    for (int j = js; j < je; ++j) {
        const int cl = clp[j];
        const float w = wp[j];
        const float* srow = sl + cl * SSTR;
        float ss = 0.f;
        #pragma unroll
        for (int c = 0; c < 4; ++c) {
            const float4 sv = *(const float4*)(srow + c * 4);
            g[c*4+0] += w * sv.x; g[c*4+1] += w * sv.y;
            g[c*4+2] += w * sv.z; g[c*4+3] += w * sv.w;
            const float d0 = sr[c*4+0] - sv.x, d1 = sr[c*4+1] - sv.y;
            const float d2 = sr[c*4+2] - sv.z, d3 = sr[c*4+3] - sv.w;
            ss += d0*d0 + d1*d1 + d2*d2 + d3*d3;
        }
        modacc += w * ss;
    }
    {
        #pragma unroll
        for (int c = 0; c < 4; ++c) {
            float4 v; v.x = g[c*4+0]; v.y = g[c*4+1]; v.z = g[c*4+2]; v.w = g[c*4+3];
            *(float4*)(gl + t * SSTR + c * 4) = v;
        }
    }
    __syncthreads();

    {
        const int k = t & 15, lg = (t >> 4) & 3;
        float p0 = 0.f, p1 = 0.f, p2 = 0.f, p3 = 0.f;
        const int r0 = wave * 64;
        for (int rr = r0; rr < r0 + 64; ++rr) {
            const float sk = sl[rr * SSTR + k];
            const float4 g4 = *(const float4*)(gl + rr * SSTR + lg * 4);
            p0 += sk * g4.x; p1 += sk * g4.y; p2 += sk * g4.z; p3 += sk * g4.w;
        }
        float* pw = padjw + wave * 256 + k * 16 + lg * 4;
        pw[0] = p0; pw[1] = p1; pw[2] = p2; pw[3] = p3;
    }

    {
        const int f = t & 63;
        const int kg = t >> 6;
        float xa0 = 0.f, xa1 = 0.f, xa2 = 0.f, xa3 = 0.f;
        const float* xp = x_to_pool + (size_t)b * NN * (64 * DIMS) + f * DIMS + d;
        #pragma unroll 4
        for (int nn2 = 0; nn2 < NN; ++nn2) {
            const float xv = xp[(size_t)nn2 * (64 * DIMS)];
            const float4 s4 = *(const float4*)(sl + nn2 * SSTR + kg * 4);
            xa0 += xv * s4.x; xa1 += xv * s4.y; xa2 += xv * s4.z; xa3 += xv * s4.w;
        }
        const float sc = 1.f / 16.f;  // K/N
        out[PX_OFF + ((size_t)((b * KK + kg * 4 + 0) * 64) + f) * DIMS + d] = xa0 * sc;
        out[PX_OFF + ((size_t)((b * KK + kg * 4 + 1) * 64) + f) * DIMS + d] = xa1 * sc;
        out[PX_OFF + ((size_t)((b * KK + kg * 4 + 2) * 64) + f) * DIMS + d] = xa2 * sc;
        out[PX_OFF + ((size_t)((b * KK + kg * 4 + 3) * 64) + f) * DIMS + d] = xa3 * sc;
    }

    #pragma unroll
    for (int off = 32; off; off >>= 1) modacc += __shfl_down(modacc, off);
    if (lane == 0) red[wave] = modacc;
    __syncthreads();
    if (t == 0) modpart[bid] = red[0] + red[1] + red[2] + red[3];

    {
        const float v = (padjw[t] + padjw[256 + t] + padjw[512 + t] + padjw[768 + t]) * (1.f / 256.f);
        out[PEA_OFF + (size_t)((b * KK + (t >> 4)) * KK + (t & 15)) * DIMS + d] = v;
    }
}

__global__ void aux_kernel(float* __restrict__ out)
{
    const int idx = blockIdx.x * 256 + threadIdx.x;
    if (idx < 2 * NTOT) {
        const int r = idx & (NTOT - 1);
        const int bb = r >> 8;
        const int j = r & 255;
        const int v = (idx < NTOT) ? (bb * KK + (j >> 4)) : (bb * KK + (j & 15));
        out[PEI_OFF + idx] = (float)v;
    } else if (idx < 2 * NTOT + NB * KK) {
        const int i = idx - 2 * NTOT;
        out[PB_OFF + i] = (float)(i >> 4);
    }
}

__global__ void loss_kernel(const float* __restrict__ entpart,
                            const float* __restrict__ modpart,
                            float* __restrict__ out)
{
    const int tid = threadIdx.x;
    float e = 0.f, m = 0.f;
    for (int i = tid; i < DIMS * NB; i += 256) { e += entpart[i]; m += modpart[i]; }
    #pragma unroll
    for (int off = 32; off; off >>= 1) { e += __shfl_down(e, off); m += __shfl_down(m, off); }
    __shared__ float er[4], mr[4];
    const int wave = tid >> 6, lane = tid & 63;
    if (lane == 0) { er[wave] = e; mr[wave] = m; }
    __syncthreads();
    if (tid == 0) {
        const float es = er[0] + er[1] + er[2] + er[3];
        const float ms = mr[0] + mr[1] + mr[2] + mr[3];
        out[LOSS_OFF] = ms / (float)NE + es / (float)(DIMS * NTOT);
    }
}

extern "C" void kernel_launch(void* const* d_in, const int* in_sizes, int n_in,
                              void* d_out, int out_size, void* d_ws, size_t ws_size,
                              hipStream_t stream)
{
    const float* x         = (const float*)d_in[0];
    const float* edge_attr = (const float*)d_in[1];
    const float* x_to_pool = (const float*)d_in[2];
    const float* Wm0 = (const float*)d_in[3];
    const float* Ws0 = (const float*)d_in[4];
    const float* b0  = (const float*)d_in[5];
    const float* Wm1 = (const float*)d_in[6];
    const float* Ws1 = (const float*)d_in[7];
    const float* b1  = (const float*)d_in[8];
    const float* Wm2 = (const float*)d_in[9];
    const float* Ws2 = (const float*)d_in[10];
    const float* b2  = (const float*)d_in[11];
    const float* fcW1= (const float*)d_in[12];
    const float* fcb1= (const float*)d_in[13];
    const float* fcW2= (const float*)d_in[14];
    const float* fcb2= (const float*)d_in[15];
    const int* edge_index = (const int*)d_in[16];
    float* out = (float*)d_out;
    char* ws = (char*)d_ws;
    float*         wrec  = (float*)(ws + WREC_WS);
    unsigned char* clrec = (unsigned char*)(ws + CLREC_WS);
    int*           iptr  = (int*)(ws + IPTR_WS);
    float*         entpart = (float*)(ws + ENT_WS);
    float*         modpart = (float*)(ws + MOD_WS);
    float*         wc    = (float*)(ws + WC_WS);
    float*         bc    = (float*)(ws + BC_WS);

    csr_build<<<dim3(NB), dim3(256), 0, stream>>>(edge_index, edge_attr, wrec, clrec, iptr);
    fc_combine<<<dim3(1), dim3(256), 0, stream>>>(fcW1, fcb1, fcW2, fcb2, wc, bc);
    gconv_kernel<<<dim3(DIMS * NB), dim3(1024), 0, stream>>>(
        x, Wm0, Ws0, b0, Wm1, Ws1, b1, Wm2, Ws2, b2,
        wc, bc, wrec, clrec, iptr, out, entpart);
    pool_kernel<<<dim3(DIMS * NB), dim3(256), 0, stream>>>(
        x_to_pool, wrec, clrec, iptr, out, out, modpart);
    aux_kernel<<<dim3((2 * NTOT + NB * KK + 255) / 256), dim3(256), 0, stream>>>(out);
    loss_kernel<<<dim3(1), dim3(256), 0, stream>>>(entpart, modpart, out);
}

// Round 11
// 596.285 us; speedup vs baseline: 2.0926x; 2.0926x over previous
//
#include <hip/hip_runtime.h>

#define DIMS 3
#define NB 256
#define NN 256
#define KK 16
#define HID 64
#define EPG 8192
#define NTOT (NB*NN)
#define NE (NB*EPG)

// d_out layout (flat concat of reference outputs, all as float)
#define PX_OFF   0          // (B*K, F, DIMS)           = 786432
#define PEI_OFF  786432     // (2, B*K*K)               = 131072
#define PEA_OFF  917504     // (B*K*K, DIMS)            = 196608
#define PB_OFF   1114112    // (B*K,)                   = 4096
#define LOSS_OFF 1118208    // scalar
#define S_OFF    1118209    // (DIMS, B, N, K)          = 3145728

// d_ws layout (bytes) — total ~27.5 MB
#define WREC_WS  0                 // float[3][NB*EPG] per-d edge weight (CSR order) = 24 MB
#define CLREC_WS 25165824          // uchar[NB*EPG] col-local index
#define IPTR_WS  27262976          // int[NB*257]
#define ENT_WS   27526144          // float[768]
#define MOD_WS   27529216          // float[768]
#define WC_WS    27532288          // float[144*16]  (fcW1 @ fcW2)
#define BC_WS    27541504          // float[16]      (fcb1 @ fcW2 + fcb2)

// ---------------- combined FC weights: Wc = fcW1@fcW2, bc = fcb1@fcW2+fcb2 ----------------
__global__ void fc_combine(const float* __restrict__ fcW1, const float* __restrict__ fcb1,
                           const float* __restrict__ fcW2, const float* __restrict__ fcb2,
                           float* __restrict__ wc, float* __restrict__ bc)
{
    const int t = threadIdx.x;
    for (int idx = t; idx < 144 * 16; idx += 256) {
        const int i = idx >> 4, k = idx & 15;
        float s = 0.f;
        for (int q = 0; q < 50; ++q) s += fcW1[i * 50 + q] * fcW2[q * 16 + k];
        wc[idx] = s;
    }
    if (t < 16) {
        float s = fcb2[t];
        for (int q = 0; q < 50; ++q) s += fcb1[q] * fcW2[q * 16 + t];
        bc[t] = s;
    }
}

// ------- CSR build: parallel deterministic counting sort (strided chunks) -------
#define HSTR 132
#define PSTR 129
__launch_bounds__(256)
__global__ void csr_build(const int* __restrict__ edge_index,
                          const float* __restrict__ edge_attr,
                          float* __restrict__ wrec, unsigned char* __restrict__ clrec,
                          int* __restrict__ indptr)
{
    __shared__ unsigned char  h[256 * HSTR];    // 33.8 KB
    __shared__ unsigned short po[256 * PSTR];   // 66.0 KB
    __shared__ int sc[256];
    const int b = blockIdx.x;
    const int t = threadIdx.x;
    const int* rowp = edge_index + (size_t)b * EPG;
    const int* colp = edge_index + (size_t)NB * EPG + (size_t)b * EPG;

    for (int i = t; i < 256 * HSTR / 4; i += 256) ((unsigned int*)h)[i] = 0u;
    __syncthreads();

    if (t < 128) {
        #pragma unroll 4
        for (int j = 0; j < 64; ++j) {
            const int r = rowp[t + 128 * j] & (NN - 1);
            h[r * HSTR + t]++;
        }
    }
    __syncthreads();

    int tot;
    {
        int s = 0;
        const unsigned int* hr = (const unsigned int*)(h + t * HSTR);
        #pragma unroll
        for (int c4 = 0; c4 < HSTR / 4; ++c4) {
            const unsigned int v = hr[c4];
            s += (v & 255) + ((v >> 8) & 255) + ((v >> 16) & 255) + (v >> 24);
        }
        tot = s;
        sc[t] = s;
    }
    __syncthreads();
    for (int ofs = 1; ofs < 256; ofs <<= 1) {
        int v = (t >= ofs) ? sc[t - ofs] : 0;
        __syncthreads();
        sc[t] += v;
        __syncthreads();
    }
    const int start = sc[t] - tot;
    indptr[b * 257 + t] = start;
    if (t == 255) indptr[b * 257 + 256] = EPG;

    {
        int run = start;
        #pragma unroll 4
        for (int c = 0; c < 128; ++c) {
            po[t * PSTR + c] = (unsigned short)run;
            run += h[t * HSTR + c];
        }
    }
    __syncthreads();

    if (t < 128) {
        const float* eap = edge_attr + (size_t)b * EPG * 3;
        float* w0 = wrec + (size_t)b * EPG;
        float* w1 = wrec + (size_t)NB * EPG + (size_t)b * EPG;
        float* w2 = wrec + 2 * (size_t)NB * EPG + (size_t)b * EPG;
        unsigned char* cdst = clrec + (size_t)b * EPG;
        #pragma unroll 2
        for (int j = 0; j < 64; ++j) {
            const int e = t + 128 * j;
            const int r = rowp[e] & (NN - 1);
            const int cl = colp[e] & (NN - 1);
            const int dest = po[r * PSTR + t]++;
            w0[dest] = eap[e * 3 + 0];
            w1[dest] = eap[e * 3 + 1];
            w2[dest] = eap[e * 3 + 2];
            cdst[dest] = (unsigned char)cl;
        }
    }
}

// -------- gconv v11: 1024 thr. Gather/dense thread = (rp,o) = (t>>3, t&7): rows {2rp,2rp+1},
// channels [8o,8o+8). FC thread = (r,kq) = (t>>2, t&3): exclusive owner of lgl[r][4kq..+4].
// Two LDS buffers (ga dies at B1); dense = two single-stream passes with weights from
// global/L1; every phase <= ~45 live VGPRs -> no spill at the 64-VGPR/1024-thr budget. --------
template<int OUTW, bool IS_L2>
__device__ __forceinline__ void layer_step(
    int t, int rp, int o, int js0, int je0, int je1,
    const float* __restrict__ wp, const unsigned char* __restrict__ clp,
    const float* __restrict__ Wm, const float* __restrict__ Ws,
    const float* __restrict__ bias, const float* __restrict__ wc, // wcomb + layer_row_off*16
    float4* hb4, float4* ab4, float* lgl)
{
    constexpr int NCO = OUTW / 8;              // outputs/thread/row: 8 (L0/L1), 2 (L2)
    const int r0 = rp * 2, r1 = r0 + 1;
    const int b0 = r0 * 16, s0 = r0 & 15;
    const int b1 = r1 * 16, s1 = r1 & 15;
    const int c0 = o * 2, c1 = o * 2 + 1;      // input float4-chunk ids

    // P1: gather agg for both rows, channels [8o, 8o+8)
    float ga0[8], ga1[8];
    #pragma unroll
    for (int u = 0; u < 8; ++u) { ga0[u] = 0.f; ga1[u] = 0.f; }
    for (int j = js0; j < je0; ++j) {
        const int cl = clp[j];
        const float w = wp[j];
        const int cb = cl * 16, cs = cl & 15;
        const float4 ha = hb4[cb + (c0 ^ cs)];
        const float4 hb = hb4[cb + (c1 ^ cs)];
        ga0[0] += w * ha.x; ga0[1] += w * ha.y; ga0[2] += w * ha.z; ga0[3] += w * ha.w;
        ga0[4] += w * hb.x; ga0[5] += w * hb.y; ga0[6] += w * hb.z; ga0[7] += w * hb.w;
    }
    for (int j = je0; j < je1; ++j) {
        const int cl = clp[j];
        const float w = wp[j];
        const int cb = cl * 16, cs = cl & 15;
        const float4 ha = hb4[cb + (c0 ^ cs)];
        const float4 hb = hb4[cb + (c1 ^ cs)];
        ga1[0] += w * ha.x; ga1[1] += w * ha.y; ga1[2] += w * ha.z; ga1[3] += w * ha.w;
        ga1[4] += w * hb.x; ga1[5] += w * hb.y; ga1[6] += w * hb.z; ga1[7] += w * hb.w;
    }
    {
        float4 v;
        v.x = ga0[0]; v.y = ga0[1]; v.z = ga0[2]; v.w = ga0[3]; ab4[b0 + (c0 ^ s0)] = v;
        v.x = ga0[4]; v.y = ga0[5]; v.z = ga0[6]; v.w = ga0[7]; ab4[b0 + (c1 ^ s0)] = v;
        v.x = ga1[0]; v.y = ga1[1]; v.z = ga1[2]; v.w = ga1[3]; ab4[b1 + (c0 ^ s1)] = v;
        v.x = ga1[4]; v.y = ga1[5]; v.z = ga1[6]; v.w = ga1[7]; ab4[b1 + (c1 ^ s1)] = v;
    }
    __syncthreads();                           // [B1] agg visible, ga dead

    // P2a: acc = bias + h@Ws (single weight stream)
    const int j0 = o * NCO;
    float acc0[NCO], acc1[NCO];
    if constexpr (NCO == 8) {
        const float4 bv0 = *(const float4*)(bias + j0);
        const float4 bv1 = *(const float4*)(bias + j0 + 4);
        acc0[0]=bv0.x; acc0[1]=bv0.y; acc0[2]=bv0.z; acc0[3]=bv0.w;
        acc0[4]=bv1.x; acc0[5]=bv1.y; acc0[6]=bv1.z; acc0[7]=bv1.w;
        #pragma unroll
        for (int u = 0; u < 8; ++u) acc1[u] = acc0[u];
    } else {
        acc0[0] = bias[j0]; acc0[1] = bias[j0 + 1];
        acc1[0] = acc0[0];  acc1[1] = acc0[1];
    }
    #pragma unroll 1
    for (int ic = 0; ic < 16; ++ic) {
        const float4 h40 = hb4[b0 + (ic ^ s0)];
        const float4 h41 = hb4[b1 + (ic ^ s1)];
        const float hv0[4] = {h40.x, h40.y, h40.z, h40.w};
        const float hv1[4] = {h41.x, h41.y, h41.z, h41.w};
        #pragma unroll
        for (int u = 0; u < 4; ++u) {
            const float* wr = Ws + (ic * 4 + u) * OUTW + j0;
            const float a0 = hv0[u], a1 = hv1[u];
            if constexpr (NCO == 8) {
                const float4 wa = *(const float4*)(wr);
                const float4 wb = *(const float4*)(wr + 4);
                acc0[0]+=a0*wa.x; acc0[1]+=a0*wa.y; acc0[2]+=a0*wa.z; acc0[3]+=a0*wa.w;
                acc0[4]+=a0*wb.x; acc0[5]+=a0*wb.y; acc0[6]+=a0*wb.z; acc0[7]+=a0*wb.w;
                acc1[0]+=a1*wa.x; acc1[1]+=a1*wa.y; acc1[2]+=a1*wa.z; acc1[3]+=a1*wa.w;
                acc1[4]+=a1*wb.x; acc1[5]+=a1*wb.y; acc1[6]+=a1*wb.z; acc1[7]+=a1*wb.w;
            } else {
                const float2 w2 = *(const float2*)(wr);
                acc0[0]+=a0*w2.x; acc0[1]+=a0*w2.y;
                acc1[0]+=a1*w2.x; acc1[1]+=a1*w2.y;
            }
        }
    }
    // P2b: acc += agg@Wm (single weight stream)
    #pragma unroll 1
    for (int ic = 0; ic < 16; ++ic) {
        const float4 a40 = ab4[b0 + (ic ^ s0)];
        const float4 a41 = ab4[b1 + (ic ^ s1)];
        const float av0[4] = {a40.x, a40.y, a40.z, a40.w};
        const float av1[4] = {a41.x, a41.y, a41.z, a41.w};
        #pragma unroll
        for (int u = 0; u < 4; ++u) {
            const float* wr = Wm + (ic * 4 + u) * OUTW + j0;
            const float a0 = av0[u], a1 = av1[u];
            if constexpr (NCO == 8) {
                const float4 wa = *(const float4*)(wr);
                const float4 wb = *(const float4*)(wr + 4);
                acc0[0]+=a0*wa.x; acc0[1]+=a0*wa.y; acc0[2]+=a0*wa.z; acc0[3]+=a0*wa.w;
                acc0[4]+=a0*wb.x; acc0[5]+=a0*wb.y; acc0[6]+=a0*wb.z; acc0[7]+=a0*wb.w;
                acc1[0]+=a1*wa.x; acc1[1]+=a1*wa.y; acc1[2]+=a1*wa.z; acc1[3]+=a1*wa.w;
                acc1[4]+=a1*wb.x; acc1[5]+=a1*wb.y; acc1[6]+=a1*wb.z; acc1[7]+=a1*wb.w;
            } else {
                const float2 w2 = *(const float2*)(wr);
                acc0[0]+=a0*w2.x; acc0[1]+=a0*w2.y;
                acc1[0]+=a1*w2.x; acc1[1]+=a1*w2.y;
            }
        }
    }
    #pragma unroll
    for (int jj = 0; jj < NCO; ++jj) {
        acc0[jj] = fmaxf(acc0[jj], 0.f);
        acc1[jj] = fmaxf(acc1[jj], 0.f);
    }
    __syncthreads();                           // [B2] all hb/ab dense reads done

    // P3: write h_next (L0/L1 -> hb4; L2 -> ab4 as float2)
    if constexpr (!IS_L2) {
        float4 v;
        v.x = acc0[0]; v.y = acc0[1]; v.z = acc0[2]; v.w = acc0[3]; hb4[b0 + (c0 ^ s0)] = v;
        v.x = acc0[4]; v.y = acc0[5]; v.z = acc0[6]; v.w = acc0[7]; hb4[b0 + (c1 ^ s0)] = v;
        v.x = acc1[0]; v.y = acc1[1]; v.z = acc1[2]; v.w = acc1[3]; hb4[b1 + (c0 ^ s1)] = v;
        v.x = acc1[4]; v.y = acc1[5]; v.z = acc1[6]; v.w = acc1[7]; hb4[b1 + (c1 ^ s1)] = v;
    } else {
        float* abf = (float*)ab4;
        const int cc = o >> 1, off = (o & 1) * 2;
        float* p0 = abf + (b0 + (cc ^ s0)) * 4 + off;
        float* p1 = abf + (b1 + (cc ^ s1)) * 4 + off;
        p0[0] = acc0[0]; p0[1] = acc0[1];
        p1[0] = acc1[0]; p1[1] = acc1[1];
    }
    __syncthreads();                           // [B3] h_next visible

    // P4: FC — thread (r,kq) owns lgl[r][kq*4..+4]; only p[4] live
    {
        const int r = t >> 2, kq = t & 3;
        const int rb = r * 16, rs = r & 15;
        float p[4] = {0.f, 0.f, 0.f, 0.f};
        if constexpr (!IS_L2) {
            #pragma unroll 2
            for (int c4 = 0; c4 < 16; ++c4) {
                const float4 v4 = hb4[rb + (c4 ^ rs)];
                const float vv[4] = {v4.x, v4.y, v4.z, v4.w};
                #pragma unroll
                for (int e = 0; e < 4; ++e) {
                    const float4 w4 = *(const float4*)(wc + (c4 * 4 + e) * 16 + kq * 4);
                    p[0] += vv[e] * w4.x; p[1] += vv[e] * w4.y;
                    p[2] += vv[e] * w4.z; p[3] += vv[e] * w4.w;
                }
            }
        } else {
            #pragma unroll 2
            for (int c4 = 0; c4 < 4; ++c4) {
                const float4 v4 = ab4[rb + (c4 ^ rs)];
                const float vv[4] = {v4.x, v4.y, v4.z, v4.w};
                #pragma unroll
                for (int e = 0; e < 4; ++e) {
                    const float4 w4 = *(const float4*)(wc + (c4 * 4 + e) * 16 + kq * 4);
                    p[0] += vv[e] * w4.x; p[1] += vv[e] * w4.y;
                    p[2] += vv[e] * w4.z; p[3] += vv[e] * w4.w;
                }
            }
        }
        float4* l4 = (float4*)lgl + r * 4 + kq;
        float4 old = *l4;
        old.x += p[0]; old.y += p[1]; old.z += p[2]; old.w += p[3];
        *l4 = old;
    }
    // no trailing barrier: next P1 only reads hb4 / writes ab4 (fenced by B2/B3);
    // lgl cells are single-owner across layers.
}

__launch_bounds__(1024)
__global__ void gconv_kernel(
    const float* __restrict__ x,
    const float* __restrict__ Wm0, const float* __restrict__ Ws0, const float* __restrict__ b0,
    const float* __restrict__ Wm1, const float* __restrict__ Ws1, const float* __restrict__ b1,
    const float* __restrict__ Wm2, const float* __restrict__ Ws2, const float* __restrict__ b2,
    const float* __restrict__ wcomb, const float* __restrict__ bcomb,
    const float* __restrict__ wrec, const unsigned char* __restrict__ clrec,
    const int* __restrict__ indptr,
    float* __restrict__ out, float* __restrict__ entpart)
{
    __shared__ float4 hb4[4096];       // h tile, XOR-chunk-swizzled (64 KB)
    __shared__ float4 ab4[4096];       // agg tile / L2-h parking (64 KB)
    __shared__ float  lgl[NN * 16];    // logits accumulator (16 KB, float4-RMW single-owner)
    __shared__ float  red[16];
    const int t = threadIdx.x;
    const int bid = blockIdx.x;
    const int d = bid >> 8;
    const int b = bid & (NB - 1);
    const int rp = t >> 3;         // row pair
    const int o = t & 7;           // channel oct
    const int lane = t & 63;
    const int wave = t >> 6;

    // stage x -> hb (swizzled) ; zero logits
    {
        const float4* xv = (const float4*)(x + (size_t)b * NN * HID);
        #pragma unroll
        for (int it = 0; it < 4; ++it) {
            const int idx = t + it * 1024;
            const int nrow = idx >> 4, c = idx & 15;
            hb4[nrow * 16 + (c ^ (nrow & 15))] = xv[idx];
        }
        #pragma unroll
        for (int it = 0; it < 4; ++it) lgl[t + it * 1024] = 0.f;
    }
    __syncthreads();   // [B0]

    const float* wp = wrec + (size_t)d * NB * EPG + (size_t)b * EPG;
    const unsigned char* clp = clrec + (size_t)b * EPG;
    const int js0 = indptr[b * 257 + rp * 2];
    const int je0 = indptr[b * 257 + rp * 2 + 1];
    const int je1 = indptr[b * 257 + rp * 2 + 2];

    layer_step<64, false>(t, rp, o, js0, je0, je1, wp, clp, Wm0 + d*HID*HID, Ws0 + d*HID*HID,
                          b0 + d*HID, wcomb,            hb4, ab4, lgl);
    layer_step<64, false>(t, rp, o, js0, je0, je1, wp, clp, Wm1 + d*HID*HID, Ws1 + d*HID*HID,
                          b1 + d*HID, wcomb + 64*16,    hb4, ab4, lgl);
    layer_step<16, true >(t, rp, o, js0, je0, je1, wp, clp, Wm2 + d*HID*KK,  Ws2 + d*HID*KK,
                          b2 + d*KK,  wcomb + 128*16,   hb4, ab4, lgl);
    __syncthreads();   // lgl complete

    // softmax + entropy: threads t<256, row = t
    float ent_local = 0.f;
    if (t < 256) {
        const int rr = t;
        float logits[KK];
        const float* Lr = lgl + rr * 16;
        #pragma unroll
        for (int k = 0; k < KK; ++k) logits[k] = Lr[k] + bcomb[k];
        float m = logits[0];
        #pragma unroll
        for (int k = 1; k < KK; ++k) m = fmaxf(m, logits[k]);
        float sum = 0.f, sv[KK];
        #pragma unroll
        for (int k = 0; k < KK; ++k) { sv[k] = expf(logits[k] - m); sum += sv[k]; }
        const float inv = 1.f / sum;
        float4* sp4 = (float4*)(out + S_OFF + ((size_t)(d * NB + b) * NN + rr) * KK);
        #pragma unroll
        for (int q4 = 0; q4 < 4; ++q4) {
            float4 v;
            const float s0 = sv[q4*4+0] * inv, s1 = sv[q4*4+1] * inv;
            const float s2 = sv[q4*4+2] * inv, s3 = sv[q4*4+3] * inv;
            v.x = s0; v.y = s1; v.z = s2; v.w = s3;
            sp4[q4] = v;
            ent_local -= s0 * logf(s0 + 1e-15f) + s1 * logf(s1 + 1e-15f)
                       + s2 * logf(s2 + 1e-15f) + s3 * logf(s3 + 1e-15f);
        }
    }
    #pragma unroll
    for (int off = 32; off; off >>= 1) ent_local += __shfl_down(ent_local, off);
    if (lane == 0) red[wave] = ent_local;
    __syncthreads();
    if (t == 0) {
        float s = 0.f;
        #pragma unroll
        for (int w = 0; w < 16; ++w) s += red[w];
        entpart[bid] = s;
    }
}

// ---------------- pool: padj = sum_r s[r] (x) G[r], G = A s ; + mod + px ----------------
#define SSTR 20
__launch_bounds__(256)
__global__ void pool_kernel(
    const float* __restrict__ x_to_pool,
    const float* __restrict__ wrec, const unsigned char* __restrict__ clrec,
    const int* __restrict__ indptr,
    const float* __restrict__ out_s, float* __restrict__ out, float* __restrict__ modpart)
{
    __shared__ float sl[NN * SSTR];       // 20 KB
    __shared__ float gl[NN * SSTR];       // 20 KB
    __shared__ float padjw[4 * 256];      // per-wave partials (deterministic merge)
    __shared__ float red[4];
    const int t = threadIdx.x;
    const int bid = blockIdx.x;
    const int d = bid >> 8;
    const int b = bid & (NB - 1);
    const int lane = t & 63;
    const int wave = t >> 6;

    {
        const float4* sp4 = (const float4*)(out_s + S_OFF + (size_t)(d * NB + b) * NN * KK);
        #pragma unroll
        for (int it = 0; it < 4; ++it) {
            const int idx = t + it * 256;
            const int nrow = idx >> 2, c = idx & 3;
            *(float4*)(sl + nrow * SSTR + c * 4) = sp4[idx];
        }
    }
    __syncthreads();

    const float* wp = wrec + (size_t)d * NB * EPG + (size_t)b * EPG;
    const unsigned char* clp = clrec + (size_t)b * EPG;
    const int js = indptr[b * 257 + t];
    const int je = indptr[b * 257 + t + 1];
    float sr[16];
    {
        #pragma unroll
        for (int c = 0; c < 4; ++c) {
            const float4 v = *(const float4*)(sl + t * SSTR + c * 4);
            sr[c*4+0] = v.x; sr[c*4+1] = v.y; sr[c*4+2] = v.z; sr[c*4+3] = v.w;
        }
    }
    float g[16];
    #pragma unroll
    for (int k = 0; k < 16; ++k) g[k] = 0.f;
    float modacc = 0.f;
    for (int j = js; j < je; ++j) {
        const int cl = clp[j];
        const float w = wp[j];
        const float* srow = sl + cl * SSTR;
        float ss = 0.f;
        #pragma unroll
        for (int c = 0; c < 4; ++c) {
            const float4 sv = *(const float4*)(srow + c * 4);
            g[c*4+0] += w * sv.x; g[c*4+1] += w * sv.y;
            g[c*4+2] += w * sv.z; g[c*4+3] += w * sv.w;
            const float d0 = sr[c*4+0] - sv.x, d1 = sr[c*4+1] - sv.y;
            const float d2 = sr[c*4+2] - sv.z, d3 = sr[c*4+3] - sv.w;
            ss += d0*d0 + d1*d1 + d2*d2 + d3*d3;
        }
        modacc += w * ss;
    }
    {
        #pragma unroll
        for (int c = 0; c < 4; ++c) {
            float4 v; v.x = g[c*4+0]; v.y = g[c*4+1]; v.z = g[c*4+2]; v.w = g[c*4+3];
            *(float4*)(gl + t * SSTR + c * 4) = v;
        }
    }
    __syncthreads();

    {
        const int k = t & 15, lg = (t >> 4) & 3;
        float p0 = 0.f, p1 = 0.f, p2 = 0.f, p3 = 0.f;
        const int r0 = wave * 64;
        for (int rr = r0; rr < r0 + 64; ++rr) {
            const float sk = sl[rr * SSTR + k];
            const float4 g4 = *(const float4*)(gl + rr * SSTR + lg * 4);
            p0 += sk * g4.x; p1 += sk * g4.y; p2 += sk * g4.z; p3 += sk * g4.w;
        }
        float* pw = padjw + wave * 256 + k * 16 + lg * 4;
        pw[0] = p0; pw[1] = p1; pw[2] = p2; pw[3] = p3;
    }

    {
        const int f = t & 63;
        const int kg = t >> 6;
        float xa0 = 0.f, xa1 = 0.f, xa2 = 0.f, xa3 = 0.f;
        const float* xp = x_to_pool + (size_t)b * NN * (64 * DIMS) + f * DIMS + d;
        #pragma unroll 4
        for (int nn2 = 0; nn2 < NN; ++nn2) {
            const float xv = xp[(size_t)nn2 * (64 * DIMS)];
            const float4 s4 = *(const float4*)(sl + nn2 * SSTR + kg * 4);
            xa0 += xv * s4.x; xa1 += xv * s4.y; xa2 += xv * s4.z; xa3 += xv * s4.w;
        }
        const float sc = 1.f / 16.f;  // K/N
        out[PX_OFF + ((size_t)((b * KK + kg * 4 + 0) * 64) + f) * DIMS + d] = xa0 * sc;
        out[PX_OFF + ((size_t)((b * KK + kg * 4 + 1) * 64) + f) * DIMS + d] = xa1 * sc;
        out[PX_OFF + ((size_t)((b * KK + kg * 4 + 2) * 64) + f) * DIMS + d] = xa2 * sc;
        out[PX_OFF + ((size_t)((b * KK + kg * 4 + 3) * 64) + f) * DIMS + d] = xa3 * sc;
    }

    #pragma unroll
    for (int off = 32; off; off >>= 1) modacc += __shfl_down(modacc, off);
    if (lane == 0) red[wave] = modacc;
    __syncthreads();
    if (t == 0) modpart[bid] = red[0] + red[1] + red[2] + red[3];

    {
        const float v = (padjw[t] + padjw[256 + t] + padjw[512 + t] + padjw[768 + t]) * (1.f / 256.f);
        out[PEA_OFF + (size_t)((b * KK + (t >> 4)) * KK + (t & 15)) * DIMS + d] = v;
    }
}

__global__ void aux_kernel(float* __restrict__ out)
{
    const int idx = blockIdx.x * 256 + threadIdx.x;
    if (idx < 2 * NTOT) {
        const int r = idx & (NTOT - 1);
        const int bb = r >> 8;
        const int j = r & 255;
        const int v = (idx < NTOT) ? (bb * KK + (j >> 4)) : (bb * KK + (j & 15));
        out[PEI_OFF + idx] = (float)v;
    } else if (idx < 2 * NTOT + NB * KK) {
        const int i = idx - 2 * NTOT;
        out[PB_OFF + i] = (float)(i >> 4);
    }
}

__global__ void loss_kernel(const float* __restrict__ entpart,
                            const float* __restrict__ modpart,
                            float* __restrict__ out)
{
    const int tid = threadIdx.x;
    float e = 0.f, m = 0.f;
    for (int i = tid; i < DIMS * NB; i += 256) { e += entpart[i]; m += modpart[i]; }
    #pragma unroll
    for (int off = 32; off; off >>= 1) { e += __shfl_down(e, off); m += __shfl_down(m, off); }
    __shared__ float er[4], mr[4];
    const int wave = tid >> 6, lane = tid & 63;
    if (lane == 0) { er[wave] = e; mr[wave] = m; }
    __syncthreads();
    if (tid == 0) {
        const float es = er[0] + er[1] + er[2] + er[3];
        const float ms = mr[0] + mr[1] + mr[2] + mr[3];
        out[LOSS_OFF] = ms / (float)NE + es / (float)(DIMS * NTOT);
    }
}

extern "C" void kernel_launch(void* const* d_in, const int* in_sizes, int n_in,
                              void* d_out, int out_size, void* d_ws, size_t ws_size,
                              hipStream_t stream)
{
    const float* x         = (const float*)d_in[0];
    const float* edge_attr = (const float*)d_in[1];
    const float* x_to_pool = (const float*)d_in[2];
    const float* Wm0 = (const float*)d_in[3];
    const float* Ws0 = (const float*)d_in[4];
    const float* b0  = (const float*)d_in[5];
    const float* Wm1 = (const float*)d_in[6];
    const float* Ws1 = (const float*)d_in[7];
    const float* b1  = (const float*)d_in[8];
    const float* Wm2 = (const float*)d_in[9];
    const float* Ws2 = (const float*)d_in[10];
    const float* b2  = (const float*)d_in[11];
    const float* fcW1= (const float*)d_in[12];
    const float* fcb1= (const float*)d_in[13];
    const float* fcW2= (const float*)d_in[14];
    const float* fcb2= (const float*)d_in[15];
    const int* edge_index = (const int*)d_in[16];
    float* out = (float*)d_out;
    char* ws = (char*)d_ws;
    float*         wrec  = (float*)(ws + WREC_WS);
    unsigned char* clrec = (unsigned char*)(ws + CLREC_WS);
    int*           iptr  = (int*)(ws + IPTR_WS);
    float*         entpart = (float*)(ws + ENT_WS);
    float*         modpart = (float*)(ws + MOD_WS);
    float*         wc    = (float*)(ws + WC_WS);
    float*         bc    = (float*)(ws + BC_WS);

    csr_build<<<dim3(NB), dim3(256), 0, stream>>>(edge_index, edge_attr, wrec, clrec, iptr);
    fc_combine<<<dim3(1), dim3(256), 0, stream>>>(fcW1, fcb1, fcW2, fcb2, wc, bc);
    gconv_kernel<<<dim3(DIMS * NB), dim3(1024), 0, stream>>>(
        x, Wm0, Ws0, b0, Wm1, Ws1, b1, Wm2, Ws2, b2,
        wc, bc, wrec, clrec, iptr, out, entpart);
    pool_kernel<<<dim3(DIMS * NB), dim3(256), 0, stream>>>(
        x_to_pool, wrec, clrec, iptr, out, out, modpart);
    aux_kernel<<<dim3((2 * NTOT + NB * KK + 255) / 256), dim3(256), 0, stream>>>(out);
    loss_kernel<<<dim3(1), dim3(256), 0, stream>>>(entpart, modpart, out);
}

// Round 12
// 581.207 us; speedup vs baseline: 2.1468x; 1.0259x over previous
//
#include <hip/hip_runtime.h>

#define DIMS 3
#define NB 256
#define NN 256
#define KK 16
#define HID 64
#define EPG 8192
#define NTOT (NB*NN)
#define NE (NB*EPG)

// d_out layout (flat concat of reference outputs, all as float)
#define PX_OFF   0          // (B*K, F, DIMS)           = 786432
#define PEI_OFF  786432     // (2, B*K*K)               = 131072
#define PEA_OFF  917504     // (B*K*K, DIMS)            = 196608
#define PB_OFF   1114112    // (B*K,)                   = 4096
#define LOSS_OFF 1118208    // scalar
#define S_OFF    1118209    // (DIMS, B, N, K)          = 3145728

// d_ws layout (bytes) — total ~27.5 MB
#define WREC_WS  0                 // float[3][NB*EPG] per-d edge weight (CSR order) = 24 MB
#define CLREC_WS 25165824          // uchar[NB*EPG] col-local index
#define IPTR_WS  27262976          // int[NB*257]
#define ENT_WS   27526144          // float[768]
#define MOD_WS   27529216          // float[768]
#define WC_WS    27532288          // float[144*16]  (fcW1 @ fcW2)
#define BC_WS    27541504          // float[16]      (fcb1 @ fcW2 + fcb2)

// ---------------- combined FC weights: Wc = fcW1@fcW2, bc = fcb1@fcW2+fcb2 ----------------
__global__ void fc_combine(const float* __restrict__ fcW1, const float* __restrict__ fcb1,
                           const float* __restrict__ fcW2, const float* __restrict__ fcb2,
                           float* __restrict__ wc, float* __restrict__ bc)
{
    const int t = threadIdx.x;
    for (int idx = t; idx < 144 * 16; idx += 256) {
        const int i = idx >> 4, k = idx & 15;
        float s = 0.f;
        for (int q = 0; q < 50; ++q) s += fcW1[i * 50 + q] * fcW2[q * 16 + k];
        wc[idx] = s;
    }
    if (t < 16) {
        float s = fcb2[t];
        for (int q = 0; q < 50; ++q) s += fcb1[q] * fcW2[q * 16 + t];
        bc[t] = s;
    }
}

// ------- CSR build: parallel deterministic counting sort (strided chunks) -------
#define HSTR 132
#define PSTR 129
__launch_bounds__(256)
__global__ void csr_build(const int* __restrict__ edge_index,
                          const float* __restrict__ edge_attr,
                          float* __restrict__ wrec, unsigned char* __restrict__ clrec,
                          int* __restrict__ indptr)
{
    __shared__ unsigned char  h[256 * HSTR];    // 33.8 KB
    __shared__ unsigned short po[256 * PSTR];   // 66.0 KB
    __shared__ int sc[256];
    const int b = blockIdx.x;
    const int t = threadIdx.x;
    const int* rowp = edge_index + (size_t)b * EPG;
    const int* colp = edge_index + (size_t)NB * EPG + (size_t)b * EPG;

    for (int i = t; i < 256 * HSTR / 4; i += 256) ((unsigned int*)h)[i] = 0u;
    __syncthreads();

    if (t < 128) {
        #pragma unroll 4
        for (int j = 0; j < 64; ++j) {
            const int r = rowp[t + 128 * j] & (NN - 1);
            h[r * HSTR + t]++;
        }
    }
    __syncthreads();

    int tot;
    {
        int s = 0;
        const unsigned int* hr = (const unsigned int*)(h + t * HSTR);
        #pragma unroll
        for (int c4 = 0; c4 < HSTR / 4; ++c4) {
            const unsigned int v = hr[c4];
            s += (v & 255) + ((v >> 8) & 255) + ((v >> 16) & 255) + (v >> 24);
        }
        tot = s;
        sc[t] = s;
    }
    __syncthreads();
    for (int ofs = 1; ofs < 256; ofs <<= 1) {
        int v = (t >= ofs) ? sc[t - ofs] : 0;
        __syncthreads();
        sc[t] += v;
        __syncthreads();
    }
    const int start = sc[t] - tot;
    indptr[b * 257 + t] = start;
    if (t == 255) indptr[b * 257 + 256] = EPG;

    {
        int run = start;
        #pragma unroll 4
        for (int c = 0; c < 128; ++c) {
            po[t * PSTR + c] = (unsigned short)run;
            run += h[t * HSTR + c];
        }
    }
    __syncthreads();

    if (t < 128) {
        const float* eap = edge_attr + (size_t)b * EPG * 3;
        float* w0 = wrec + (size_t)b * EPG;
        float* w1 = wrec + (size_t)NB * EPG + (size_t)b * EPG;
        float* w2 = wrec + 2 * (size_t)NB * EPG + (size_t)b * EPG;
        unsigned char* cdst = clrec + (size_t)b * EPG;
        #pragma unroll 2
        for (int j = 0; j < 64; ++j) {
            const int e = t + 128 * j;
            const int r = rowp[e] & (NN - 1);
            const int cl = colp[e] & (NN - 1);
            const int dest = po[r * PSTR + t]++;
            w0[dest] = eap[e * 3 + 0];
            w1[dest] = eap[e * 3 + 1];
            w2[dest] = eap[e * 3 + 2];
            cdst[dest] = (unsigned char)cl;
        }
    }
}

// -------- gconv v12: 1024 thr, ONE 64 KB h buffer -> 2 blocks/CU (8 waves/SIMD).
// Gather/dense thread = (rp,o); FC thread = (fr,fkq) with a PERSISTENT p[4] register
// accumulator across layers (no logits LDS). Sequence per layer (4 barriers):
//   P1 gather ga + P2 acc=bias+h@Ws | B1 | P3 agg->hb | B2 | P4 acc+=agg@Wm,relu | B3 |
//   P5 h_next->hb | B4 | FC p += h_next@Wc.  Weights stream from global/L1. --------
template<int OUTW, bool IS_L2>
__device__ __forceinline__ void layer_step(
    int rp, int o, int fr, int fkq, int js0, int je0, int je1,
    const float* __restrict__ wp, const unsigned char* __restrict__ clp,
    const float* __restrict__ Wm, const float* __restrict__ Ws,
    const float* __restrict__ bias, const float* __restrict__ wc, // wcomb + layer_row_off*16
    float4* hb4, float* p)
{
    constexpr int NCO = OUTW / 8;              // outputs/thread/row: 8 (L0/L1), 2 (L2)
    const int r0 = rp * 2, r1 = r0 + 1;
    const int b0 = r0 * 16, s0 = r0 & 15;
    const int b1 = r1 * 16, s1 = r1 & 15;
    const int c0 = o * 2, c1 = o * 2 + 1;      // float4-chunk ids owned by this thread

    // P1: gather agg for both rows, channels [8o, 8o+8)
    float ga0[8], ga1[8];
    #pragma unroll
    for (int u = 0; u < 8; ++u) { ga0[u] = 0.f; ga1[u] = 0.f; }
    for (int j = js0; j < je0; ++j) {
        const int cl = clp[j];
        const float w = wp[j];
        const int cb = cl * 16, cs = cl & 15;
        const float4 ha = hb4[cb + (c0 ^ cs)];
        const float4 hb = hb4[cb + (c1 ^ cs)];
        ga0[0] += w * ha.x; ga0[1] += w * ha.y; ga0[2] += w * ha.z; ga0[3] += w * ha.w;
        ga0[4] += w * hb.x; ga0[5] += w * hb.y; ga0[6] += w * hb.z; ga0[7] += w * hb.w;
    }
    for (int j = je0; j < je1; ++j) {
        const int cl = clp[j];
        const float w = wp[j];
        const int cb = cl * 16, cs = cl & 15;
        const float4 ha = hb4[cb + (c0 ^ cs)];
        const float4 hb = hb4[cb + (c1 ^ cs)];
        ga1[0] += w * ha.x; ga1[1] += w * ha.y; ga1[2] += w * ha.z; ga1[3] += w * ha.w;
        ga1[4] += w * hb.x; ga1[5] += w * hb.y; ga1[6] += w * hb.z; ga1[7] += w * hb.w;
    }

    // P2: acc = bias + h@Ws (single weight stream from global/L1)
    const int j0 = o * NCO;
    float acc0[NCO], acc1[NCO];
    if constexpr (NCO == 8) {
        const float4 bv0 = *(const float4*)(bias + j0);
        const float4 bv1 = *(const float4*)(bias + j0 + 4);
        acc0[0]=bv0.x; acc0[1]=bv0.y; acc0[2]=bv0.z; acc0[3]=bv0.w;
        acc0[4]=bv1.x; acc0[5]=bv1.y; acc0[6]=bv1.z; acc0[7]=bv1.w;
        #pragma unroll
        for (int u = 0; u < 8; ++u) acc1[u] = acc0[u];
    } else {
        acc0[0] = bias[j0]; acc0[1] = bias[j0 + 1];
        acc1[0] = acc0[0];  acc1[1] = acc0[1];
    }
    #pragma unroll 1
    for (int ic = 0; ic < 16; ++ic) {
        const float4 h40 = hb4[b0 + (ic ^ s0)];
        const float4 h41 = hb4[b1 + (ic ^ s1)];
        const float hv0[4] = {h40.x, h40.y, h40.z, h40.w};
        const float hv1[4] = {h41.x, h41.y, h41.z, h41.w};
        #pragma unroll
        for (int u = 0; u < 4; ++u) {
            const float* wr = Ws + (ic * 4 + u) * OUTW + j0;
            const float a0 = hv0[u], a1 = hv1[u];
            if constexpr (NCO == 8) {
                const float4 wa = *(const float4*)(wr);
                const float4 wb = *(const float4*)(wr + 4);
                acc0[0]+=a0*wa.x; acc0[1]+=a0*wa.y; acc0[2]+=a0*wa.z; acc0[3]+=a0*wa.w;
                acc0[4]+=a0*wb.x; acc0[5]+=a0*wb.y; acc0[6]+=a0*wb.z; acc0[7]+=a0*wb.w;
                acc1[0]+=a1*wa.x; acc1[1]+=a1*wa.y; acc1[2]+=a1*wa.z; acc1[3]+=a1*wa.w;
                acc1[4]+=a1*wb.x; acc1[5]+=a1*wb.y; acc1[6]+=a1*wb.z; acc1[7]+=a1*wb.w;
            } else {
                const float2 w2 = *(const float2*)(wr);
                acc0[0]+=a0*w2.x; acc0[1]+=a0*w2.y;
                acc1[0]+=a1*w2.x; acc1[1]+=a1*w2.y;
            }
        }
    }
    __syncthreads();                           // [B1] all hb reads (gather + P2) done

    // P3: write agg over h (rows r0,r1, this thread's chunks)
    {
        float4 v;
        v.x = ga0[0]; v.y = ga0[1]; v.z = ga0[2]; v.w = ga0[3]; hb4[b0 + (c0 ^ s0)] = v;
        v.x = ga0[4]; v.y = ga0[5]; v.z = ga0[6]; v.w = ga0[7]; hb4[b0 + (c1 ^ s0)] = v;
        v.x = ga1[0]; v.y = ga1[1]; v.z = ga1[2]; v.w = ga1[3]; hb4[b1 + (c0 ^ s1)] = v;
        v.x = ga1[4]; v.y = ga1[5]; v.z = ga1[6]; v.w = ga1[7]; hb4[b1 + (c1 ^ s1)] = v;
    }
    __syncthreads();                           // [B2] agg visible

    // P4: acc += agg@Wm (single weight stream)
    #pragma unroll 1
    for (int ic = 0; ic < 16; ++ic) {
        const float4 a40 = hb4[b0 + (ic ^ s0)];
        const float4 a41 = hb4[b1 + (ic ^ s1)];
        const float av0[4] = {a40.x, a40.y, a40.z, a40.w};
        const float av1[4] = {a41.x, a41.y, a41.z, a41.w};
        #pragma unroll
        for (int u = 0; u < 4; ++u) {
            const float* wr = Wm + (ic * 4 + u) * OUTW + j0;
            const float a0 = av0[u], a1 = av1[u];
            if constexpr (NCO == 8) {
                const float4 wa = *(const float4*)(wr);
                const float4 wb = *(const float4*)(wr + 4);
                acc0[0]+=a0*wa.x; acc0[1]+=a0*wa.y; acc0[2]+=a0*wa.z; acc0[3]+=a0*wa.w;
                acc0[4]+=a0*wb.x; acc0[5]+=a0*wb.y; acc0[6]+=a0*wb.z; acc0[7]+=a0*wb.w;
                acc1[0]+=a1*wa.x; acc1[1]+=a1*wa.y; acc1[2]+=a1*wa.z; acc1[3]+=a1*wa.w;
                acc1[4]+=a1*wb.x; acc1[5]+=a1*wb.y; acc1[6]+=a1*wb.z; acc1[7]+=a1*wb.w;
            } else {
                const float2 w2 = *(const float2*)(wr);
                acc0[0]+=a0*w2.x; acc0[1]+=a0*w2.y;
                acc1[0]+=a1*w2.x; acc1[1]+=a1*w2.y;
            }
        }
    }
    #pragma unroll
    for (int jj = 0; jj < NCO; ++jj) {
        acc0[jj] = fmaxf(acc0[jj], 0.f);
        acc1[jj] = fmaxf(acc1[jj], 0.f);
    }
    __syncthreads();                           // [B3] agg reads done

    // P5: write h_next (L0/L1: this thread's chunks; L2: float2 into chunks 0-3)
    if constexpr (!IS_L2) {
        float4 v;
        v.x = acc0[0]; v.y = acc0[1]; v.z = acc0[2]; v.w = acc0[3]; hb4[b0 + (c0 ^ s0)] = v;
        v.x = acc0[4]; v.y = acc0[5]; v.z = acc0[6]; v.w = acc0[7]; hb4[b0 + (c1 ^ s0)] = v;
        v.x = acc1[0]; v.y = acc1[1]; v.z = acc1[2]; v.w = acc1[3]; hb4[b1 + (c0 ^ s1)] = v;
        v.x = acc1[4]; v.y = acc1[5]; v.z = acc1[6]; v.w = acc1[7]; hb4[b1 + (c1 ^ s1)] = v;
    } else {
        float* hbf = (float*)hb4;
        const int cc = o >> 1, off = (o & 1) * 2;
        float* p0 = hbf + (b0 + (cc ^ s0)) * 4 + off;
        float* p1 = hbf + (b1 + (cc ^ s1)) * 4 + off;
        p0[0] = acc0[0]; p0[1] = acc0[1];
        p1[0] = acc1[0]; p1[1] = acc1[1];
    }
    __syncthreads();                           // [B4] h_next visible

    // FC: thread (fr,fkq) accumulates p[4] += h_next[fr][:] @ Wc[:, fkq*4..+4]
    {
        const int rb = fr * 16, rs = fr & 15;
        if constexpr (!IS_L2) {
            #pragma unroll 2
            for (int c4 = 0; c4 < 16; ++c4) {
                const float4 v4 = hb4[rb + (c4 ^ rs)];
                const float vv[4] = {v4.x, v4.y, v4.z, v4.w};
                #pragma unroll
                for (int e = 0; e < 4; ++e) {
                    const float4 w4 = *(const float4*)(wc + (c4 * 4 + e) * 16 + fkq * 4);
                    p[0] += vv[e] * w4.x; p[1] += vv[e] * w4.y;
                    p[2] += vv[e] * w4.z; p[3] += vv[e] * w4.w;
                }
            }
        } else {
            #pragma unroll 2
            for (int c4 = 0; c4 < 4; ++c4) {
                const float4 v4 = hb4[rb + (c4 ^ rs)];
                const float vv[4] = {v4.x, v4.y, v4.z, v4.w};
                #pragma unroll
                for (int e = 0; e < 4; ++e) {
                    const float4 w4 = *(const float4*)(wc + (c4 * 4 + e) * 16 + fkq * 4);
                    p[0] += vv[e] * w4.x; p[1] += vv[e] * w4.y;
                    p[2] += vv[e] * w4.z; p[3] += vv[e] * w4.w;
                }
            }
        }
    }
    // no trailing barrier: next layer's P1/P2 only READ hb (ok concurrent with FC reads);
    // next P3 writes are fenced by next layer's B1.
}

__launch_bounds__(1024)
__global__ void gconv_kernel(
    const float* __restrict__ x,
    const float* __restrict__ Wm0, const float* __restrict__ Ws0, const float* __restrict__ b0,
    const float* __restrict__ Wm1, const float* __restrict__ Ws1, const float* __restrict__ b1,
    const float* __restrict__ Wm2, const float* __restrict__ Ws2, const float* __restrict__ b2,
    const float* __restrict__ wcomb, const float* __restrict__ bcomb,
    const float* __restrict__ wrec, const unsigned char* __restrict__ clrec,
    const int* __restrict__ indptr,
    float* __restrict__ out, float* __restrict__ entpart)
{
    __shared__ float4 hb4[4096];       // h tile, XOR-chunk-swizzled (64 KB) — the ONLY big buffer
    __shared__ float  red[16];
    const int t = threadIdx.x;
    const int bid = blockIdx.x;
    const int d = bid >> 8;
    const int b = bid & (NB - 1);
    const int rp = t >> 3;         // row pair
    const int o = t & 7;           // channel oct
    const int fr = t >> 2;         // FC row
    const int fkq = t & 3;         // FC k-quad
    const int lane = t & 63;
    const int wave = t >> 6;

    // stage x -> hb (swizzled)
    {
        const float4* xv = (const float4*)(x + (size_t)b * NN * HID);
        #pragma unroll
        for (int it = 0; it < 4; ++it) {
            const int idx = t + it * 1024;
            const int nrow = idx >> 4, c = idx & 15;
            hb4[nrow * 16 + (c ^ (nrow & 15))] = xv[idx];
        }
    }
    float p[4] = {0.f, 0.f, 0.f, 0.f};   // persistent FC accumulator (thread (fr,fkq))
    __syncthreads();   // [B0]

    const float* wp = wrec + (size_t)d * NB * EPG + (size_t)b * EPG;
    const unsigned char* clp = clrec + (size_t)b * EPG;
    const int js0 = indptr[b * 257 + rp * 2];
    const int je0 = indptr[b * 257 + rp * 2 + 1];
    const int je1 = indptr[b * 257 + rp * 2 + 2];

    layer_step<64, false>(rp, o, fr, fkq, js0, je0, je1, wp, clp, Wm0 + d*HID*HID,
                          Ws0 + d*HID*HID, b0 + d*HID, wcomb,          hb4, p);
    layer_step<64, false>(rp, o, fr, fkq, js0, je0, je1, wp, clp, Wm1 + d*HID*HID,
                          Ws1 + d*HID*HID, b1 + d*HID, wcomb + 64*16,  hb4, p);
    layer_step<16, true >(rp, o, fr, fkq, js0, je0, je1, wp, clp, Wm2 + d*HID*KK,
                          Ws2 + d*HID*KK,  b2 + d*KK,  wcomb + 128*16, hb4, p);

    __syncthreads();   // [B5] all FC reads of hb done — safe to overwrite with logits
    // exchange p -> hb scratch (stride-17 rows to spread banks)
    {
        float* hbf = (float*)hb4;
        float* dst = hbf + fr * 17 + fkq * 4;
        dst[0] = p[0]; dst[1] = p[1]; dst[2] = p[2]; dst[3] = p[3];
    }
    __syncthreads();   // [B6] logits visible

    // softmax + entropy: threads t<256, row = t
    float ent_local = 0.f;
    if (t < 256) {
        const int rr = t;
        const float* Lr = (const float*)hb4 + rr * 17;
        float logits[KK];
        #pragma unroll
        for (int k = 0; k < KK; ++k) logits[k] = Lr[k] + bcomb[k];
        float m = logits[0];
        #pragma unroll
        for (int k = 1; k < KK; ++k) m = fmaxf(m, logits[k]);
        float sum = 0.f, sv[KK];
        #pragma unroll
        for (int k = 0; k < KK; ++k) { sv[k] = expf(logits[k] - m); sum += sv[k]; }
        const float inv = 1.f / sum;
        float4* sp4 = (float4*)(out + S_OFF + ((size_t)(d * NB + b) * NN + rr) * KK);
        #pragma unroll
        for (int q4 = 0; q4 < 4; ++q4) {
            float4 v;
            const float s0 = sv[q4*4+0] * inv, s1 = sv[q4*4+1] * inv;
            const float s2 = sv[q4*4+2] * inv, s3 = sv[q4*4+3] * inv;
            v.x = s0; v.y = s1; v.z = s2; v.w = s3;
            sp4[q4] = v;
            ent_local -= s0 * logf(s0 + 1e-15f) + s1 * logf(s1 + 1e-15f)
                       + s2 * logf(s2 + 1e-15f) + s3 * logf(s3 + 1e-15f);
        }
    }
    #pragma unroll
    for (int off = 32; off; off >>= 1) ent_local += __shfl_down(ent_local, off);
    if (lane == 0) red[wave] = ent_local;
    __syncthreads();
    if (t == 0) {
        float s = 0.f;
        #pragma unroll
        for (int w = 0; w < 16; ++w) s += red[w];
        entpart[bid] = s;
    }
}

// ---------------- pool: padj = sum_r s[r] (x) G[r], G = A s ; + mod + px ----------------
#define SSTR 20
__launch_bounds__(256)
__global__ void pool_kernel(
    const float* __restrict__ x_to_pool,
    const float* __restrict__ wrec, const unsigned char* __restrict__ clrec,
    const int* __restrict__ indptr,
    const float* __restrict__ out_s, float* __restrict__ out, float* __restrict__ modpart)
{
    __shared__ float sl[NN * SSTR];       // 20 KB
    __shared__ float gl[NN * SSTR];       // 20 KB
    __shared__ float padjw[4 * 256];      // per-wave partials (deterministic merge)
    __shared__ float red[4];
    const int t = threadIdx.x;
    const int bid = blockIdx.x;
    const int d = bid >> 8;
    const int b = bid & (NB - 1);
    const int lane = t & 63;
    const int wave = t >> 6;

    {
        const float4* sp4 = (const float4*)(out_s + S_OFF + (size_t)(d * NB + b) * NN * KK);
        #pragma unroll
        for (int it = 0; it < 4; ++it) {
            const int idx = t + it * 256;
            const int nrow = idx >> 2, c = idx & 3;
            *(float4*)(sl + nrow * SSTR + c * 4) = sp4[idx];
        }
    }
    __syncthreads();

    const float* wp = wrec + (size_t)d * NB * EPG + (size_t)b * EPG;
    const unsigned char* clp = clrec + (size_t)b * EPG;
    const int js = indptr[b * 257 + t];
    const int je = indptr[b * 257 + t + 1];
    float sr[16];
    {
        #pragma unroll
        for (int c = 0; c < 4; ++c) {
            const float4 v = *(const float4*)(sl + t * SSTR + c * 4);
            sr[c*4+0] = v.x; sr[c*4+1] = v.y; sr[c*4+2] = v.z; sr[c*4+3] = v.w;
        }
    }
    float g[16];
    #pragma unroll
    for (int k = 0; k < 16; ++k) g[k] = 0.f;
    float modacc = 0.f;
    for (int j = js; j < je; ++j) {
        const int cl = clp[j];
        const float w = wp[j];
        const float* srow = sl + cl * SSTR;
        float ss = 0.f;
        #pragma unroll
        for (int c = 0; c < 4; ++c) {
            const float4 sv = *(const float4*)(srow + c * 4);
            g[c*4+0] += w * sv.x; g[c*4+1] += w * sv.y;
            g[c*4+2] += w * sv.z; g[c*4+3] += w * sv.w;
            const float d0 = sr[c*4+0] - sv.x, d1 = sr[c*4+1] - sv.y;
            const float d2 = sr[c*4+2] - sv.z, d3 = sr[c*4+3] - sv.w;
            ss += d0*d0 + d1*d1 + d2*d2 + d3*d3;
        }
        modacc += w * ss;
    }
    {
        #pragma unroll
        for (int c = 0; c < 4; ++c) {
            float4 v; v.x = g[c*4+0]; v.y = g[c*4+1]; v.z = g[c*4+2]; v.w = g[c*4+3];
            *(float4*)(gl + t * SSTR + c * 4) = v;
        }
    }
    __syncthreads();

    {
        const int k = t & 15, lg = (t >> 4) & 3;
        float p0 = 0.f, p1 = 0.f, p2 = 0.f, p3 = 0.f;
        const int r0 = wave * 64;
        for (int rr = r0; rr < r0 + 64; ++rr) {
            const float sk = sl[rr * SSTR + k];
            const float4 g4 = *(const float4*)(gl + rr * SSTR + lg * 4);
            p0 += sk * g4.x; p1 += sk * g4.y; p2 += sk * g4.z; p3 += sk * g4.w;
        }
        float* pw = padjw + wave * 256 + k * 16 + lg * 4;
        pw[0] = p0; pw[1] = p1; pw[2] = p2; pw[3] = p3;
    }

    {
        const int f = t & 63;
        const int kg = t >> 6;
        float xa0 = 0.f, xa1 = 0.f, xa2 = 0.f, xa3 = 0.f;
        const float* xp = x_to_pool + (size_t)b * NN * (64 * DIMS) + f * DIMS + d;
        #pragma unroll 4
        for (int nn2 = 0; nn2 < NN; ++nn2) {
            const float xv = xp[(size_t)nn2 * (64 * DIMS)];
            const float4 s4 = *(const float4*)(sl + nn2 * SSTR + kg * 4);
            xa0 += xv * s4.x; xa1 += xv * s4.y; xa2 += xv * s4.z; xa3 += xv * s4.w;
        }
        const float sc = 1.f / 16.f;  // K/N
        out[PX_OFF + ((size_t)((b * KK + kg * 4 + 0) * 64) + f) * DIMS + d] = xa0 * sc;
        out[PX_OFF + ((size_t)((b * KK + kg * 4 + 1) * 64) + f) * DIMS + d] = xa1 * sc;
        out[PX_OFF + ((size_t)((b * KK + kg * 4 + 2) * 64) + f) * DIMS + d] = xa2 * sc;
        out[PX_OFF + ((size_t)((b * KK + kg * 4 + 3) * 64) + f) * DIMS + d] = xa3 * sc;
    }

    #pragma unroll
    for (int off = 32; off; off >>= 1) modacc += __shfl_down(modacc, off);
    if (lane == 0) red[wave] = modacc;
    __syncthreads();
    if (t == 0) modpart[bid] = red[0] + red[1] + red[2] + red[3];

    {
        const float v = (padjw[t] + padjw[256 + t] + padjw[512 + t] + padjw[768 + t]) * (1.f / 256.f);
        out[PEA_OFF + (size_t)((b * KK + (t >> 4)) * KK + (t & 15)) * DIMS + d] = v;
    }
}

__global__ void aux_kernel(float* __restrict__ out)
{
    const int idx = blockIdx.x * 256 + threadIdx.x;
    if (idx < 2 * NTOT) {
        const int r = idx & (NTOT - 1);
        const int bb = r >> 8;
        const int j = r & 255;
        const int v = (idx < NTOT) ? (bb * KK + (j >> 4)) : (bb * KK + (j & 15));
        out[PEI_OFF + idx] = (float)v;
    } else if (idx < 2 * NTOT + NB * KK) {
        const int i = idx - 2 * NTOT;
        out[PB_OFF + i] = (float)(i >> 4);
    }
}

__global__ void loss_kernel(const float* __restrict__ entpart,
                            const float* __restrict__ modpart,
                            float* __restrict__ out)
{
    const int tid = threadIdx.x;
    float e = 0.f, m = 0.f;
    for (int i = tid; i < DIMS * NB; i += 256) { e += entpart[i]; m += modpart[i]; }
    #pragma unroll
    for (int off = 32; off; off >>= 1) { e += __shfl_down(e, off); m += __shfl_down(m, off); }
    __shared__ float er[4], mr[4];
    const int wave = tid >> 6, lane = tid & 63;
    if (lane == 0) { er[wave] = e; mr[wave] = m; }
    __syncthreads();
    if (tid == 0) {
        const float es = er[0] + er[1] + er[2] + er[3];
        const float ms = mr[0] + mr[1] + mr[2] + mr[3];
        out[LOSS_OFF] = ms / (float)NE + es / (float)(DIMS * NTOT);
    }
}

extern "C" void kernel_launch(void* const* d_in, const int* in_sizes, int n_in,
                              void* d_out, int out_size, void* d_ws, size_t ws_size,
                              hipStream_t stream)
{
    const float* x         = (const float*)d_in[0];
    const float* edge_attr = (const float*)d_in[1];
    const float* x_to_pool = (const float*)d_in[2];
    const float* Wm0 = (const float*)d_in[3];
    const float* Ws0 = (const float*)d_in[4];
    const float* b0  = (const float*)d_in[5];
    const float* Wm1 = (const float*)d_in[6];
    const float* Ws1 = (const float*)d_in[7];
    const float* b1  = (const float*)d_in[8];
    const float* Wm2 = (const float*)d_in[9];
    const float* Ws2 = (const float*)d_in[10];
    const float* b2  = (const float*)d_in[11];
    const float* fcW1= (const float*)d_in[12];
    const float* fcb1= (const float*)d_in[13];
    const float* fcW2= (const float*)d_in[14];
    const float* fcb2= (const float*)d_in[15];
    const int* edge_index = (const int*)d_in[16];
    float* out = (float*)d_out;
    char* ws = (char*)d_ws;
    float*         wrec  = (float*)(ws + WREC_WS);
    unsigned char* clrec = (unsigned char*)(ws + CLREC_WS);
    int*           iptr  = (int*)(ws + IPTR_WS);
    float*         entpart = (float*)(ws + ENT_WS);
    float*         modpart = (float*)(ws + MOD_WS);
    float*         wc    = (float*)(ws + WC_WS);
    float*         bc    = (float*)(ws + BC_WS);

    csr_build<<<dim3(NB), dim3(256), 0, stream>>>(edge_index, edge_attr, wrec, clrec, iptr);
    fc_combine<<<dim3(1), dim3(256), 0, stream>>>(fcW1, fcb1, fcW2, fcb2, wc, bc);
    gconv_kernel<<<dim3(DIMS * NB), dim3(1024), 0, stream>>>(
        x, Wm0, Ws0, b0, Wm1, Ws1, b1, Wm2, Ws2, b2,
        wc, bc, wrec, clrec, iptr, out, entpart);
    pool_kernel<<<dim3(DIMS * NB), dim3(256), 0, stream>>>(
        x_to_pool, wrec, clrec, iptr, out, out, modpart);
    aux_kernel<<<dim3((2 * NTOT + NB * KK + 255) / 256), dim3(256), 0, stream>>>(out);
    loss_kernel<<<dim3(1), dim3(256), 0, stream>>>(entpart, modpart, out);
}

// Round 13
// 578.784 us; speedup vs baseline: 2.1558x; 1.0042x over previous
//
#include <hip/hip_runtime.h>

#define DIMS 3
#define NB 256
#define NN 256
#define KK 16
#define HID 64
#define EPG 8192
#define NTOT (NB*NN)
#define NE (NB*EPG)

// d_out layout (flat concat of reference outputs, all as float)
#define PX_OFF   0          // (B*K, F, DIMS)           = 786432
#define PEI_OFF  786432     // (2, B*K*K)               = 131072
#define PEA_OFF  917504     // (B*K*K, DIMS)            = 196608
#define PB_OFF   1114112    // (B*K,)                   = 4096
#define LOSS_OFF 1118208    // scalar
#define S_OFF    1118209    // (DIMS, B, N, K)          = 3145728

// d_ws layout (bytes) — total ~27.5 MB
#define WREC_WS  0                 // float[3][NB*EPG] per-d edge weight (CSR order) = 24 MB
#define CLREC_WS 25165824          // uchar[NB*EPG] col-local index
#define IPTR_WS  27262976          // int[NB*257]
#define ENT_WS   27526144          // float[768]
#define MOD_WS   27529216          // float[768]
#define WC_WS    27532288          // float[144*16]  (fcW1 @ fcW2)
#define BC_WS    27541504          // float[16]      (fcb1 @ fcW2 + fcb2)

// ---------------- combined FC weights: Wc = fcW1@fcW2, bc = fcb1@fcW2+fcb2 ----------------
__global__ void fc_combine(const float* __restrict__ fcW1, const float* __restrict__ fcb1,
                           const float* __restrict__ fcW2, const float* __restrict__ fcb2,
                           float* __restrict__ wc, float* __restrict__ bc)
{
    const int t = threadIdx.x;
    for (int idx = t; idx < 144 * 16; idx += 256) {
        const int i = idx >> 4, k = idx & 15;
        float s = 0.f;
        for (int q = 0; q < 50; ++q) s += fcW1[i * 50 + q] * fcW2[q * 16 + k];
        wc[idx] = s;
    }
    if (t < 16) {
        float s = fcb2[t];
        for (int q = 0; q < 50; ++q) s += fcb1[q] * fcW2[q * 16 + t];
        bc[t] = s;
    }
}

// ------- CSR build: parallel deterministic counting sort (strided chunks) -------
#define HSTR 132
#define PSTR 129
__launch_bounds__(256)
__global__ void csr_build(const int* __restrict__ edge_index,
                          const float* __restrict__ edge_attr,
                          float* __restrict__ wrec, unsigned char* __restrict__ clrec,
                          int* __restrict__ indptr)
{
    __shared__ unsigned char  h[256 * HSTR];    // 33.8 KB
    __shared__ unsigned short po[256 * PSTR];   // 66.0 KB
    __shared__ int sc[256];
    const int b = blockIdx.x;
    const int t = threadIdx.x;
    const int* rowp = edge_index + (size_t)b * EPG;
    const int* colp = edge_index + (size_t)NB * EPG + (size_t)b * EPG;

    for (int i = t; i < 256 * HSTR / 4; i += 256) ((unsigned int*)h)[i] = 0u;
    __syncthreads();

    if (t < 128) {
        #pragma unroll 4
        for (int j = 0; j < 64; ++j) {
            const int r = rowp[t + 128 * j] & (NN - 1);
            h[r * HSTR + t]++;
        }
    }
    __syncthreads();

    int tot;
    {
        int s = 0;
        const unsigned int* hr = (const unsigned int*)(h + t * HSTR);
        #pragma unroll
        for (int c4 = 0; c4 < HSTR / 4; ++c4) {
            const unsigned int v = hr[c4];
            s += (v & 255) + ((v >> 8) & 255) + ((v >> 16) & 255) + (v >> 24);
        }
        tot = s;
        sc[t] = s;
    }
    __syncthreads();
    for (int ofs = 1; ofs < 256; ofs <<= 1) {
        int v = (t >= ofs) ? sc[t - ofs] : 0;
        __syncthreads();
        sc[t] += v;
        __syncthreads();
    }
    const int start = sc[t] - tot;
    indptr[b * 257 + t] = start;
    if (t == 255) indptr[b * 257 + 256] = EPG;

    {
        int run = start;
        #pragma unroll 4
        for (int c = 0; c < 128; ++c) {
            po[t * PSTR + c] = (unsigned short)run;
            run += h[t * HSTR + c];
        }
    }
    __syncthreads();

    if (t < 128) {
        const float* eap = edge_attr + (size_t)b * EPG * 3;
        float* w0 = wrec + (size_t)b * EPG;
        float* w1 = wrec + (size_t)NB * EPG + (size_t)b * EPG;
        float* w2 = wrec + 2 * (size_t)NB * EPG + (size_t)b * EPG;
        unsigned char* cdst = clrec + (size_t)b * EPG;
        #pragma unroll 2
        for (int j = 0; j < 64; ++j) {
            const int e = t + 128 * j;
            const int r = rowp[e] & (NN - 1);
            const int cl = colp[e] & (NN - 1);
            const int dest = po[r * PSTR + t]++;
            w0[dest] = eap[e * 3 + 0];
            w1[dest] = eap[e * 3 + 1];
            w2[dest] = eap[e * 3 + 2];
            cdst[dest] = (unsigned char)cl;
        }
    }
}

// -------- gconv v13: v12 + conflict-free chunk mapping. Thread (rp,o) owns chunks
// (o, o+8): within an 8-lane row-group the chunk residues (o^s) mod 8 are a permutation
// of 0..7, so every gather ds_read_b128 covers all 32 banks exactly once (min 8 phases).
// Dense output columns follow: (4o..4o+4) and (4o+32..4o+36). --------
template<int OUTW, bool IS_L2>
__device__ __forceinline__ void layer_step(
    int rp, int o, int fr, int fkq, int js0, int je0, int je1,
    const float* __restrict__ wp, const unsigned char* __restrict__ clp,
    const float* __restrict__ Wm, const float* __restrict__ Ws,
    const float* __restrict__ bias, const float* __restrict__ wc, // wcomb + layer_row_off*16
    float4* hb4, float* p)
{
    constexpr int NCO = OUTW / 8;              // outputs/thread/row: 8 (L0/L1), 2 (L2)
    const int r0 = rp * 2, r1 = r0 + 1;
    const int b0 = r0 * 16, s0 = r0 & 15;
    const int b1 = r1 * 16, s1 = r1 & 15;
    const int c0 = o, c1 = o + 8;              // conflict-free chunk pair

    // P1: gather agg for both rows, channels [4o,4o+4) and [4o+32,4o+36)
    float ga0[8], ga1[8];
    #pragma unroll
    for (int u = 0; u < 8; ++u) { ga0[u] = 0.f; ga1[u] = 0.f; }
    for (int j = js0; j < je0; ++j) {
        const int cl = clp[j];
        const float w = wp[j];
        const int cb = cl * 16, cs = cl & 15;
        const float4 ha = hb4[cb + (c0 ^ cs)];
        const float4 hb = hb4[cb + (c1 ^ cs)];
        ga0[0] += w * ha.x; ga0[1] += w * ha.y; ga0[2] += w * ha.z; ga0[3] += w * ha.w;
        ga0[4] += w * hb.x; ga0[5] += w * hb.y; ga0[6] += w * hb.z; ga0[7] += w * hb.w;
    }
    for (int j = je0; j < je1; ++j) {
        const int cl = clp[j];
        const float w = wp[j];
        const int cb = cl * 16, cs = cl & 15;
        const float4 ha = hb4[cb + (c0 ^ cs)];
        const float4 hb = hb4[cb + (c1 ^ cs)];
        ga1[0] += w * ha.x; ga1[1] += w * ha.y; ga1[2] += w * ha.z; ga1[3] += w * ha.w;
        ga1[4] += w * hb.x; ga1[5] += w * hb.y; ga1[6] += w * hb.z; ga1[7] += w * hb.w;
    }

    // P2: acc = bias + h@Ws (single weight stream from global/L1)
    const int jA = o * 4;                      // column group A
    const int jB = o * 4 + 32;                 // column group B (chunk o+8)
    const int j0L2 = o * NCO;                  // L2 column base
    float acc0[NCO == 8 ? 8 : 2], acc1[NCO == 8 ? 8 : 2];
    if constexpr (NCO == 8) {
        const float4 bv0 = *(const float4*)(bias + jA);
        const float4 bv1 = *(const float4*)(bias + jB);
        acc0[0]=bv0.x; acc0[1]=bv0.y; acc0[2]=bv0.z; acc0[3]=bv0.w;
        acc0[4]=bv1.x; acc0[5]=bv1.y; acc0[6]=bv1.z; acc0[7]=bv1.w;
        #pragma unroll
        for (int u = 0; u < 8; ++u) acc1[u] = acc0[u];
    } else {
        acc0[0] = bias[j0L2]; acc0[1] = bias[j0L2 + 1];
        acc1[0] = acc0[0];    acc1[1] = acc0[1];
    }
    #pragma unroll 1
    for (int ic = 0; ic < 16; ++ic) {
        const float4 h40 = hb4[b0 + (ic ^ s0)];
        const float4 h41 = hb4[b1 + (ic ^ s1)];
        const float hv0[4] = {h40.x, h40.y, h40.z, h40.w};
        const float hv1[4] = {h41.x, h41.y, h41.z, h41.w};
        #pragma unroll
        for (int u = 0; u < 4; ++u) {
            const float* wr = Ws + (ic * 4 + u) * OUTW;
            const float a0 = hv0[u], a1 = hv1[u];
            if constexpr (NCO == 8) {
                const float4 wa = *(const float4*)(wr + jA);
                const float4 wb = *(const float4*)(wr + jB);
                acc0[0]+=a0*wa.x; acc0[1]+=a0*wa.y; acc0[2]+=a0*wa.z; acc0[3]+=a0*wa.w;
                acc0[4]+=a0*wb.x; acc0[5]+=a0*wb.y; acc0[6]+=a0*wb.z; acc0[7]+=a0*wb.w;
                acc1[0]+=a1*wa.x; acc1[1]+=a1*wa.y; acc1[2]+=a1*wa.z; acc1[3]+=a1*wa.w;
                acc1[4]+=a1*wb.x; acc1[5]+=a1*wb.y; acc1[6]+=a1*wb.z; acc1[7]+=a1*wb.w;
            } else {
                const float2 w2 = *(const float2*)(wr + j0L2);
                acc0[0]+=a0*w2.x; acc0[1]+=a0*w2.y;
                acc1[0]+=a1*w2.x; acc1[1]+=a1*w2.y;
            }
        }
    }
    __syncthreads();                           // [B1] all hb reads (gather + P2) done

    // P3: write agg over h (rows r0,r1, chunks o and o+8) — conflict-free
    {
        float4 v;
        v.x = ga0[0]; v.y = ga0[1]; v.z = ga0[2]; v.w = ga0[3]; hb4[b0 + (c0 ^ s0)] = v;
        v.x = ga0[4]; v.y = ga0[5]; v.z = ga0[6]; v.w = ga0[7]; hb4[b0 + (c1 ^ s0)] = v;
        v.x = ga1[0]; v.y = ga1[1]; v.z = ga1[2]; v.w = ga1[3]; hb4[b1 + (c0 ^ s1)] = v;
        v.x = ga1[4]; v.y = ga1[5]; v.z = ga1[6]; v.w = ga1[7]; hb4[b1 + (c1 ^ s1)] = v;
    }
    __syncthreads();                           // [B2] agg visible

    // P4: acc += agg@Wm (single weight stream)
    #pragma unroll 1
    for (int ic = 0; ic < 16; ++ic) {
        const float4 a40 = hb4[b0 + (ic ^ s0)];
        const float4 a41 = hb4[b1 + (ic ^ s1)];
        const float av0[4] = {a40.x, a40.y, a40.z, a40.w};
        const float av1[4] = {a41.x, a41.y, a41.z, a41.w};
        #pragma unroll
        for (int u = 0; u < 4; ++u) {
            const float* wr = Wm + (ic * 4 + u) * OUTW;
            const float a0 = av0[u], a1 = av1[u];
            if constexpr (NCO == 8) {
                const float4 wa = *(const float4*)(wr + jA);
                const float4 wb = *(const float4*)(wr + jB);
                acc0[0]+=a0*wa.x; acc0[1]+=a0*wa.y; acc0[2]+=a0*wa.z; acc0[3]+=a0*wa.w;
                acc0[4]+=a0*wb.x; acc0[5]+=a0*wb.y; acc0[6]+=a0*wb.z; acc0[7]+=a0*wb.w;
                acc1[0]+=a1*wa.x; acc1[1]+=a1*wa.y; acc1[2]+=a1*wa.z; acc1[3]+=a1*wa.w;
                acc1[4]+=a1*wb.x; acc1[5]+=a1*wb.y; acc1[6]+=a1*wb.z; acc1[7]+=a1*wb.w;
            } else {
                const float2 w2 = *(const float2*)(wr + j0L2);
                acc0[0]+=a0*w2.x; acc0[1]+=a0*w2.y;
                acc1[0]+=a1*w2.x; acc1[1]+=a1*w2.y;
            }
        }
    }
    #pragma unroll
    for (int jj = 0; jj < NCO; ++jj) {
        acc0[jj] = fmaxf(acc0[jj], 0.f);
        acc1[jj] = fmaxf(acc1[jj], 0.f);
    }
    __syncthreads();                           // [B3] agg reads done

    // P5: write h_next (L0/L1: cols jA->chunk o, jB->chunk o+8; L2: float2 into chunks 0-3)
    if constexpr (!IS_L2) {
        float4 v;
        v.x = acc0[0]; v.y = acc0[1]; v.z = acc0[2]; v.w = acc0[3]; hb4[b0 + (c0 ^ s0)] = v;
        v.x = acc0[4]; v.y = acc0[5]; v.z = acc0[6]; v.w = acc0[7]; hb4[b0 + (c1 ^ s0)] = v;
        v.x = acc1[0]; v.y = acc1[1]; v.z = acc1[2]; v.w = acc1[3]; hb4[b1 + (c0 ^ s1)] = v;
        v.x = acc1[4]; v.y = acc1[5]; v.z = acc1[6]; v.w = acc1[7]; hb4[b1 + (c1 ^ s1)] = v;
    } else {
        float* hbf = (float*)hb4;
        const int cc = o >> 1, off = (o & 1) * 2;
        float* p0 = hbf + (b0 + (cc ^ s0)) * 4 + off;
        float* p1 = hbf + (b1 + (cc ^ s1)) * 4 + off;
        p0[0] = acc0[0]; p0[1] = acc0[1];
        p1[0] = acc1[0]; p1[1] = acc1[1];
    }
    __syncthreads();                           // [B4] h_next visible

    // FC: thread (fr,fkq) accumulates p[4] += h_next[fr][:] @ Wc[:, fkq*4..+4]
    {
        const int rb = fr * 16, rs = fr & 15;
        if constexpr (!IS_L2) {
            #pragma unroll 2
            for (int c4 = 0; c4 < 16; ++c4) {
                const float4 v4 = hb4[rb + (c4 ^ rs)];
                const float vv[4] = {v4.x, v4.y, v4.z, v4.w};
                #pragma unroll
                for (int e = 0; e < 4; ++e) {
                    const float4 w4 = *(const float4*)(wc + (c4 * 4 + e) * 16 + fkq * 4);
                    p[0] += vv[e] * w4.x; p[1] += vv[e] * w4.y;
                    p[2] += vv[e] * w4.z; p[3] += vv[e] * w4.w;
                }
            }
        } else {
            #pragma unroll 2
            for (int c4 = 0; c4 < 4; ++c4) {
                const float4 v4 = hb4[rb + (c4 ^ rs)];
                const float vv[4] = {v4.x, v4.y, v4.z, v4.w};
                #pragma unroll
                for (int e = 0; e < 4; ++e) {
                    const float4 w4 = *(const float4*)(wc + (c4 * 4 + e) * 16 + fkq * 4);
                    p[0] += vv[e] * w4.x; p[1] += vv[e] * w4.y;
                    p[2] += vv[e] * w4.z; p[3] += vv[e] * w4.w;
                }
            }
        }
    }
    // no trailing barrier: next layer's P1/P2 only READ hb; next P3 writes fenced by next B1.
}

__launch_bounds__(1024)
__global__ void gconv_kernel(
    const float* __restrict__ x,
    const float* __restrict__ Wm0, const float* __restrict__ Ws0, const float* __restrict__ b0,
    const float* __restrict__ Wm1, const float* __restrict__ Ws1, const float* __restrict__ b1,
    const float* __restrict__ Wm2, const float* __restrict__ Ws2, const float* __restrict__ b2,
    const float* __restrict__ wcomb, const float* __restrict__ bcomb,
    const float* __restrict__ wrec, const unsigned char* __restrict__ clrec,
    const int* __restrict__ indptr,
    float* __restrict__ out, float* __restrict__ entpart)
{
    __shared__ float4 hb4[4096];       // h tile, XOR-chunk-swizzled (64 KB)
    __shared__ float  red[16];
    const int t = threadIdx.x;
    const int bid = blockIdx.x;
    const int d = bid >> 8;
    const int b = bid & (NB - 1);
    const int rp = t >> 3;         // row pair
    const int o = t & 7;           // chunk owner (chunks o, o+8)
    const int fr = t >> 2;         // FC row
    const int fkq = t & 3;         // FC k-quad
    const int lane = t & 63;
    const int wave = t >> 6;

    // stage x -> hb (swizzled)
    {
        const float4* xv = (const float4*)(x + (size_t)b * NN * HID);
        #pragma unroll
        for (int it = 0; it < 4; ++it) {
            const int idx = t + it * 1024;
            const int nrow = idx >> 4, c = idx & 15;
            hb4[nrow * 16 + (c ^ (nrow & 15))] = xv[idx];
        }
    }
    float p[4] = {0.f, 0.f, 0.f, 0.f};   // persistent FC accumulator (thread (fr,fkq))
    __syncthreads();   // [B0]

    const float* wp = wrec + (size_t)d * NB * EPG + (size_t)b * EPG;
    const unsigned char* clp = clrec + (size_t)b * EPG;
    const int js0 = indptr[b * 257 + rp * 2];
    const int je0 = indptr[b * 257 + rp * 2 + 1];
    const int je1 = indptr[b * 257 + rp * 2 + 2];

    layer_step<64, false>(rp, o, fr, fkq, js0, je0, je1, wp, clp, Wm0 + d*HID*HID,
                          Ws0 + d*HID*HID, b0 + d*HID, wcomb,          hb4, p);
    layer_step<64, false>(rp, o, fr, fkq, js0, je0, je1, wp, clp, Wm1 + d*HID*HID,
                          Ws1 + d*HID*HID, b1 + d*HID, wcomb + 64*16,  hb4, p);
    layer_step<16, true >(rp, o, fr, fkq, js0, je0, je1, wp, clp, Wm2 + d*HID*KK,
                          Ws2 + d*HID*KK,  b2 + d*KK,  wcomb + 128*16, hb4, p);

    __syncthreads();   // [B5] all FC reads of hb done — safe to overwrite with logits
    {
        float* hbf = (float*)hb4;
        float* dst = hbf + fr * 17 + fkq * 4;
        dst[0] = p[0]; dst[1] = p[1]; dst[2] = p[2]; dst[3] = p[3];
    }
    __syncthreads();   // [B6] logits visible

    // softmax + entropy: threads t<256, row = t
    float ent_local = 0.f;
    if (t < 256) {
        const int rr = t;
        const float* Lr = (const float*)hb4 + rr * 17;
        float logits[KK];
        #pragma unroll
        for (int k = 0; k < KK; ++k) logits[k] = Lr[k] + bcomb[k];
        float m = logits[0];
        #pragma unroll
        for (int k = 1; k < KK; ++k) m = fmaxf(m, logits[k]);
        float sum = 0.f, sv[KK];
        #pragma unroll
        for (int k = 0; k < KK; ++k) { sv[k] = expf(logits[k] - m); sum += sv[k]; }
        const float inv = 1.f / sum;
        float4* sp4 = (float4*)(out + S_OFF + ((size_t)(d * NB + b) * NN + rr) * KK);
        #pragma unroll
        for (int q4 = 0; q4 < 4; ++q4) {
            float4 v;
            const float s0 = sv[q4*4+0] * inv, s1 = sv[q4*4+1] * inv;
            const float s2 = sv[q4*4+2] * inv, s3 = sv[q4*4+3] * inv;
            v.x = s0; v.y = s1; v.z = s2; v.w = s3;
            sp4[q4] = v;
            ent_local -= s0 * logf(s0 + 1e-15f) + s1 * logf(s1 + 1e-15f)
                       + s2 * logf(s2 + 1e-15f) + s3 * logf(s3 + 1e-15f);
        }
    }
    #pragma unroll
    for (int off = 32; off; off >>= 1) ent_local += __shfl_down(ent_local, off);
    if (lane == 0) red[wave] = ent_local;
    __syncthreads();
    if (t == 0) {
        float s = 0.f;
        #pragma unroll
        for (int w = 0; w < 16; ++w) s += red[w];
        entpart[bid] = s;
    }
}

// ---------------- pool: padj = sum_r s[r] (x) G[r], G = A s ; + mod + px ----------------
#define SSTR 20
__launch_bounds__(256)
__global__ void pool_kernel(
    const float* __restrict__ x_to_pool,
    const float* __restrict__ wrec, const unsigned char* __restrict__ clrec,
    const int* __restrict__ indptr,
    const float* __restrict__ out_s, float* __restrict__ out, float* __restrict__ modpart)
{
    __shared__ float sl[NN * SSTR];       // 20 KB
    __shared__ float gl[NN * SSTR];       // 20 KB
    __shared__ float padjw[4 * 256];      // per-wave partials (deterministic merge)
    __shared__ float red[4];
    const int t = threadIdx.x;
    const int bid = blockIdx.x;
    const int d = bid >> 8;
    const int b = bid & (NB - 1);
    const int lane = t & 63;
    const int wave = t >> 6;

    {
        const float4* sp4 = (const float4*)(out_s + S_OFF + (size_t)(d * NB + b) * NN * KK);
        #pragma unroll
        for (int it = 0; it < 4; ++it) {
            const int idx = t + it * 256;
            const int nrow = idx >> 2, c = idx & 3;
            *(float4*)(sl + nrow * SSTR + c * 4) = sp4[idx];
        }
    }
    __syncthreads();

    const float* wp = wrec + (size_t)d * NB * EPG + (size_t)b * EPG;
    const unsigned char* clp = clrec + (size_t)b * EPG;
    const int js = indptr[b * 257 + t];
    const int je = indptr[b * 257 + t + 1];
    float sr[16];
    {
        #pragma unroll
        for (int c = 0; c < 4; ++c) {
            const float4 v = *(const float4*)(sl + t * SSTR + c * 4);
            sr[c*4+0] = v.x; sr[c*4+1] = v.y; sr[c*4+2] = v.z; sr[c*4+3] = v.w;
        }
    }
    float g[16];
    #pragma unroll
    for (int k = 0; k < 16; ++k) g[k] = 0.f;
    float modacc = 0.f;
    for (int j = js; j < je; ++j) {
        const int cl = clp[j];
        const float w = wp[j];
        const float* srow = sl + cl * SSTR;
        float ss = 0.f;
        #pragma unroll
        for (int c = 0; c < 4; ++c) {
            const float4 sv = *(const float4*)(srow + c * 4);
            g[c*4+0] += w * sv.x; g[c*4+1] += w * sv.y;
            g[c*4+2] += w * sv.z; g[c*4+3] += w * sv.w;
            const float d0 = sr[c*4+0] - sv.x, d1 = sr[c*4+1] - sv.y;
            const float d2 = sr[c*4+2] - sv.z, d3 = sr[c*4+3] - sv.w;
            ss += d0*d0 + d1*d1 + d2*d2 + d3*d3;
        }
        modacc += w * ss;
    }
    {
        #pragma unroll
        for (int c = 0; c < 4; ++c) {
            float4 v; v.x = g[c*4+0]; v.y = g[c*4+1]; v.z = g[c*4+2]; v.w = g[c*4+3];
            *(float4*)(gl + t * SSTR + c * 4) = v;
        }
    }
    __syncthreads();

    {
        const int k = t & 15, lg = (t >> 4) & 3;
        float p0 = 0.f, p1 = 0.f, p2 = 0.f, p3 = 0.f;
        const int r0 = wave * 64;
        for (int rr = r0; rr < r0 + 64; ++rr) {
            const float sk = sl[rr * SSTR + k];
            const float4 g4 = *(const float4*)(gl + rr * SSTR + lg * 4);
            p0 += sk * g4.x; p1 += sk * g4.y; p2 += sk * g4.z; p3 += sk * g4.w;
        }
        float* pw = padjw + wave * 256 + k * 16 + lg * 4;
        pw[0] = p0; pw[1] = p1; pw[2] = p2; pw[3] = p3;
    }

    {
        const int f = t & 63;
        const int kg = t >> 6;
        float xa0 = 0.f, xa1 = 0.f, xa2 = 0.f, xa3 = 0.f;
        const float* xp = x_to_pool + (size_t)b * NN * (64 * DIMS) + f * DIMS + d;
        #pragma unroll 4
        for (int nn2 = 0; nn2 < NN; ++nn2) {
            const float xv = xp[(size_t)nn2 * (64 * DIMS)];
            const float4 s4 = *(const float4*)(sl + nn2 * SSTR + kg * 4);
            xa0 += xv * s4.x; xa1 += xv * s4.y; xa2 += xv * s4.z; xa3 += xv * s4.w;
        }
        const float sc = 1.f / 16.f;  // K/N
        out[PX_OFF + ((size_t)((b * KK + kg * 4 + 0) * 64) + f) * DIMS + d] = xa0 * sc;
        out[PX_OFF + ((size_t)((b * KK + kg * 4 + 1) * 64) + f) * DIMS + d] = xa1 * sc;
        out[PX_OFF + ((size_t)((b * KK + kg * 4 + 2) * 64) + f) * DIMS + d] = xa2 * sc;
        out[PX_OFF + ((size_t)((b * KK + kg * 4 + 3) * 64) + f) * DIMS + d] = xa3 * sc;
    }

    #pragma unroll
    for (int off = 32; off; off >>= 1) modacc += __shfl_down(modacc, off);
    if (lane == 0) red[wave] = modacc;
    __syncthreads();
    if (t == 0) modpart[bid] = red[0] + red[1] + red[2] + red[3];

    {
        const float v = (padjw[t] + padjw[256 + t] + padjw[512 + t] + padjw[768 + t]) * (1.f / 256.f);
        out[PEA_OFF + (size_t)((b * KK + (t >> 4)) * KK + (t & 15)) * DIMS + d] = v;
    }
}

__global__ void aux_kernel(float* __restrict__ out)
{
    const int idx = blockIdx.x * 256 + threadIdx.x;
    if (idx < 2 * NTOT) {
        const int r = idx & (NTOT - 1);
        const int bb = r >> 8;
        const int j = r & 255;
        const int v = (idx < NTOT) ? (bb * KK + (j >> 4)) : (bb * KK + (j & 15));
        out[PEI_OFF + idx] = (float)v;
    } else if (idx < 2 * NTOT + NB * KK) {
        const int i = idx - 2 * NTOT;
        out[PB_OFF + i] = (float)(i >> 4);
    }
}

__global__ void loss_kernel(const float* __restrict__ entpart,
                            const float* __restrict__ modpart,
                            float* __restrict__ out)
{
    const int tid = threadIdx.x;
    float e = 0.f, m = 0.f;
    for (int i = tid; i < DIMS * NB; i += 256) { e += entpart[i]; m += modpart[i]; }
    #pragma unroll
    for (int off = 32; off; off >>= 1) { e += __shfl_down(e, off); m += __shfl_down(m, off); }
    __shared__ float er[4], mr[4];
    const int wave = tid >> 6, lane = tid & 63;
    if (lane == 0) { er[wave] = e; mr[wave] = m; }
    __syncthreads();
    if (tid == 0) {
        const float es = er[0] + er[1] + er[2] + er[3];
        const float ms = mr[0] + mr[1] + mr[2] + mr[3];
        out[LOSS_OFF] = ms / (float)NE + es / (float)(DIMS * NTOT);
    }
}

extern "C" void kernel_launch(void* const* d_in, const int* in_sizes, int n_in,
                              void* d_out, int out_size, void* d_ws, size_t ws_size,
                              hipStream_t stream)
{
    const float* x         = (const float*)d_in[0];
    const float* edge_attr = (const float*)d_in[1];
    const float* x_to_pool = (const float*)d_in[2];
    const float* Wm0 = (const float*)d_in[3];
    const float* Ws0 = (const float*)d_in[4];
    const float* b0  = (const float*)d_in[5];
    const float* Wm1 = (const float*)d_in[6];
    const float* Ws1 = (const float*)d_in[7];
    const float* b1  = (const float*)d_in[8];
    const float* Wm2 = (const float*)d_in[9];
    const float* Ws2 = (const float*)d_in[10];
    const float* b2  = (const float*)d_in[11];
    const float* fcW1= (const float*)d_in[12];
    const float* fcb1= (const float*)d_in[13];
    const float* fcW2= (const float*)d_in[14];
    const float* fcb2= (const float*)d_in[15];
    const int* edge_index = (const int*)d_in[16];
    float* out = (float*)d_out;
    char* ws = (char*)d_ws;
    float*         wrec  = (float*)(ws + WREC_WS);
    unsigned char* clrec = (unsigned char*)(ws + CLREC_WS);
    int*           iptr  = (int*)(ws + IPTR_WS);
    float*         entpart = (float*)(ws + ENT_WS);
    float*         modpart = (float*)(ws + MOD_WS);
    float*         wc    = (float*)(ws + WC_WS);
    float*         bc    = (float*)(ws + BC_WS);

    csr_build<<<dim3(NB), dim3(256), 0, stream>>>(edge_index, edge_attr, wrec, clrec, iptr);
    fc_combine<<<dim3(1), dim3(256), 0, stream>>>(fcW1, fcb1, fcW2, fcb2, wc, bc);
    gconv_kernel<<<dim3(DIMS * NB), dim3(1024), 0, stream>>>(
        x, Wm0, Ws0, b0, Wm1, Ws1, b1, Wm2, Ws2, b2,
        wc, bc, wrec, clrec, iptr, out, entpart);
    pool_kernel<<<dim3(DIMS * NB), dim3(256), 0, stream>>>(
        x_to_pool, wrec, clrec, iptr, out, out, modpart);
    aux_kernel<<<dim3((2 * NTOT + NB * KK + 255) / 256), dim3(256), 0, stream>>>(out);
    loss_kernel<<<dim3(1), dim3(256), 0, stream>>>(entpart, modpart, out);
}